// Round 11
// baseline (200.072 us; speedup 1.0000x reference)
//
#include <hip/hip_runtime.h>
#include <math.h>

#define DF 128
#define NPB 256   // nodes per bucket (partition path)
#define EPB 4096  // edges per passA/hist block
#define CAP 7168  // passB LDS image capacity (edges)

typedef __attribute__((ext_vector_type(8))) short bf16x8;
typedef __attribute__((ext_vector_type(4))) float f32x4;

__device__ __forceinline__ float bf2f(uint u) {
    union { uint i; float f; } v; v.i = u << 16; return v.f;
}
__device__ __forceinline__ uint f2bf(float f) {  // round-to-nearest-even
    union { float f; uint i; } v; v.f = f;
    return (v.i + 0x7fffu + ((v.i >> 16) & 1u)) >> 16;
}

// ---- fused prep: cvt_x (float4) + cvtW + per-block bucket hist (no atomics, no memset) ----

__global__ void prep_k(const float* __restrict__ x, uint* __restrict__ xb, int n4,
                       const float* __restrict__ W1, const float* __restrict__ W2,
                       uint* __restrict__ Wt1, uint* __restrict__ Wt2,
                       const int* __restrict__ dst, int* __restrict__ bhist, int E,
                       int cvtxB) {
    __shared__ int lh[256];
    int b = blockIdx.x;
    int t = threadIdx.x;
    if (b < cvtxB) {
        int i = b * 256 + t;
        if (i < n4) {
            float4 v = ((const float4*)x)[i];
            uint2 o;
            o.x = f2bf(v.x) | (f2bf(v.y) << 16);
            o.y = f2bf(v.z) | (f2bf(v.w) << 16);
            ((uint2*)xb)[i] = o;
        }
    } else if (b < cvtxB + 64) {
        int i = (b - cvtxB) * 256 + t;  // 0..16383
        const float* W = (i < 8192) ? W1 : W2;
        uint* Wt = (i < 8192) ? Wt1 : Wt2;
        int j = i & 8191;
        int n = j >> 6, kk = j & 63;
        Wt[n * 64 + kk] = f2bf(W[(2 * kk) * DF + n]) | (f2bf(W[(2 * kk + 1) * DF + n]) << 16);
    } else {
        // bucket-level histogram: EPB edges per block, LDS bins, streamed out per-block
        int hb = b - cvtxB - 64;
        int base = hb * EPB;
        lh[t] = 0;
        __syncthreads();
#pragma unroll
        for (int k = 0; k < EPB / 256; ++k) {
            int i = base + k * 256 + t;
            if (i < E) atomicAdd(&lh[dst[i] >> 8], 1);
        }
        __syncthreads();
        bhist[hb * 256 + t] = lh[t];
    }
}

// ---------------- partitioned CSR fill ----------------
// Pass A: block-local counting sort of a 4096-edge chunk by dst bucket, write
// per-bucket runs into staging (bucket-major layout). Computes its own global
// staging bases deterministically from bhist (no global atomics, no bscan).
__global__ __launch_bounds__(256) void passA_k(
    const int* __restrict__ src, const int* __restrict__ dst,
    const float* __restrict__ ew, const int* __restrict__ bhist, int histB,
    int* __restrict__ bkoff, uint2* __restrict__ stage, int E) {
    __shared__ int lhist[256];
    __shared__ int lscan[256];
    __shared__ int lcur[256];
    __shared__ int gbase[256];
    __shared__ int sm[256];
    __shared__ unsigned char lbk[EPB];
    __shared__ uint2 img[EPB];
    int t = threadIdx.x;
    int hb = blockIdx.x;
    int base = hb * EPB;
    int cnt = min(EPB, E - base);

    // stage edges into registers
    uint ps[16], pw[16];
    int pb[16];
#pragma unroll
    for (int k = 0; k < 16; ++k) {
        int i = base + k * 256 + t;
        pb[k] = -1;
        if (i < E) {
            int d = dst[i];
            pb[k] = d >> 8;  // NPB=256
            ps[k] = (uint)src[i] | ((uint)(d & 255) << 23);
            pw[k] = __float_as_uint(ew[i]);
        }
    }

    // column sum over chunks + prefix before own chunk + own count
    int colsum = 0, pre = 0, own = 0;
    for (int h = 0; h < histB; ++h) {
        int v = bhist[h * 256 + t];
        colsum += v;
        if (h < hb) pre += v;
        if (h == hb) own = v;
    }
    // scan 1: bucket offsets (bkoff) from colsum
    sm[t] = colsum;
    __syncthreads();
    for (int off = 1; off < 256; off <<= 1) {
        int u = (t >= off) ? sm[t - off] : 0;
        __syncthreads();
        sm[t] += u;
        __syncthreads();
    }
    int bkx = sm[t] - colsum;  // exclusive bucket base
    gbase[t] = bkx + pre;      // this chunk's staging base for bucket t
    if (hb == 0) {
        bkoff[t] = bkx;
        if (t == 255) bkoff[256] = sm[255];
    }
    __syncthreads();
    // scan 2: local (within-chunk) positions from own
    sm[t] = own;
    __syncthreads();
    for (int off = 1; off < 256; off <<= 1) {
        int u = (t >= off) ? sm[t - off] : 0;
        __syncthreads();
        sm[t] += u;
        __syncthreads();
    }
    lhist[t] = own;
    lscan[t] = sm[t];        // inclusive
    lcur[t] = sm[t] - own;   // exclusive
    __syncthreads();

    // counting-sort scatter into LDS image
#pragma unroll
    for (int k = 0; k < 16; ++k) {
        if (pb[k] >= 0) {
            int p = atomicAdd(&lcur[pb[k]], 1);
            img[p] = make_uint2(ps[k], pw[k]);
            lbk[p] = (unsigned char)pb[k];
        }
    }
    __syncthreads();
    // coalesced copy-out to bucket-major staging
    for (int i = t; i < cnt; i += 256) {
        int bk = lbk[i];
        stage[gbase[bk] + (i - (lscan[bk] - lhist[bk]))] = img[i];
    }
}

// Pass B: one block per bucket. Builds the node-level CSR locally (LDS
// histogram + scan -> rowptr), scatters staged edges into an LDS image,
// copies out coalesced.
__global__ __launch_bounds__(256) void passB_k(
    const uint2* __restrict__ stage, const int* __restrict__ bkoff,
    int* __restrict__ rowptr, int* __restrict__ cursor,
    int2* __restrict__ adj, int N, int nbk) {
    __shared__ int lhist[256];
    __shared__ int lpre[256];
    __shared__ int lcur[256];
    __shared__ uint2 img[CAP];
    int t = threadIdx.x;
    int b = blockIdx.x;
    int nb0 = b * NPB;
    int nn = min(NPB, N - nb0);
    int ebase = bkoff[b];
    int ecnt = bkoff[b + 1] - ebase;
    lhist[t] = 0;
    __syncthreads();
    for (int i = t; i < ecnt; i += 256) {
        uint2 e = stage[ebase + i];
        atomicAdd(&lhist[(e.x >> 23) & 255], 1);
    }
    __syncthreads();
    int v = lhist[t];
    lpre[t] = v;
    __syncthreads();
    for (int off = 1; off < 256; off <<= 1) {
        int u = (t >= off) ? lpre[t - off] : 0;
        __syncthreads();
        lpre[t] += u;
        __syncthreads();
    }
    int myoff = lpre[t] - v;  // exclusive prefix within bucket
    lcur[t] = myoff;
    if (t < nn) {
        rowptr[nb0 + t] = ebase + myoff;
        cursor[nb0 + t] = ebase + myoff;
    }
    if (b == nbk - 1 && t == 0) rowptr[N] = ebase + ecnt;
    __syncthreads();
    if (ecnt <= CAP) {
        for (int i = t; i < ecnt; i += 256) {
            uint2 e = stage[ebase + i];
            int p = atomicAdd(&lcur[(e.x >> 23) & 255], 1);
            img[p] = make_uint2(e.x & 0x7fffffu, e.y);
        }
        __syncthreads();
        for (int i = t; i < ecnt; i += 256) {
            uint2 e = img[i];
            adj[ebase + i] = make_int2((int)e.x, (int)e.y);
        }
    } else {  // statistically unreachable; correctness fallback
        for (int i = t; i < ecnt; i += 256) {
            uint2 e = stage[ebase + i];
            int dl = (e.x >> 23) & 255;
            int p = atomicAdd(&cursor[nb0 + dl], 1);
            adj[p] = make_int2((int)(e.x & 0x7fffffu), (int)e.y);
        }
    }
}

// ---------------- generic fallback path (N > 65536 only) ----------------

__global__ void histn_k(const int* __restrict__ dst, int* __restrict__ cnt, int E) {
    int i = blockIdx.x * blockDim.x + threadIdx.x;
    if (i < E) atomicAdd(&cnt[dst[i]], 1);
}

__global__ void partial_k(const int* __restrict__ cnt, int* __restrict__ bsum, int N) {
    int t = threadIdx.x, b = blockIdx.x;
    int base = b * 1024 + t * 4;
    int s = 0;
    if (base + 4 <= N) {
        int4 v = *(const int4*)(cnt + base);
        s = v.x + v.y + v.z + v.w;
    } else {
        for (int j = 0; j < 4; ++j)
            if (base + j < N) s += cnt[base + j];
    }
    __shared__ int sm[256];
    sm[t] = s;
    __syncthreads();
    for (int off = 128; off > 0; off >>= 1) {
        if (t < off) sm[t] += sm[t + off];
        __syncthreads();
    }
    if (t == 0) bsum[b] = sm[0];
}

__global__ void scanb_k(const int* __restrict__ bsum, int* __restrict__ boff,
                        int* __restrict__ rowptr, int nb, int N) {
    int t = threadIdx.x;
    int v = (t < nb) ? bsum[t] : 0;
    __shared__ int sm[256];
    sm[t] = v;
    __syncthreads();
    for (int off = 1; off < 256; off <<= 1) {
        int u = (t >= off) ? sm[t - off] : 0;
        __syncthreads();
        sm[t] += u;
        __syncthreads();
    }
    if (t < nb) boff[t] = sm[t] - v;
    if (t == 255) rowptr[N] = sm[255];
}

__global__ void rowfill_k(const int* __restrict__ cnt, const int* __restrict__ boff,
                          int* __restrict__ rowptr, int* __restrict__ cursor, int N) {
    int t = threadIdx.x, b = blockIdx.x;
    int base = b * 1024 + t * 4;
    int c0 = 0, c1 = 0, c2 = 0, c3 = 0;
    if (base + 4 <= N) {
        int4 v = *(const int4*)(cnt + base);
        c0 = v.x; c1 = v.y; c2 = v.z; c3 = v.w;
    } else {
        if (base + 0 < N) c0 = cnt[base + 0];
        if (base + 1 < N) c1 = cnt[base + 1];
        if (base + 2 < N) c2 = cnt[base + 2];
        if (base + 3 < N) c3 = cnt[base + 3];
    }
    int s = c0 + c1 + c2 + c3;
    __shared__ int sm[256];
    sm[t] = s;
    __syncthreads();
    for (int off = 1; off < 256; off <<= 1) {
        int u = (t >= off) ? sm[t - off] : 0;
        __syncthreads();
        sm[t] += u;
        __syncthreads();
    }
    int run = boff[b] + sm[t] - s;
    if (base + 0 < N) { rowptr[base + 0] = run; cursor[base + 0] = run; run += c0; }
    if (base + 1 < N) { rowptr[base + 1] = run; cursor[base + 1] = run; run += c1; }
    if (base + 2 < N) { rowptr[base + 2] = run; cursor[base + 2] = run; run += c2; }
    if (base + 3 < N) { rowptr[base + 3] = run; cursor[base + 3] = run; run += c3; }
}

__global__ void fill_k(const int* __restrict__ src, const int* __restrict__ dst,
                       const float* __restrict__ ew, int* __restrict__ cursor,
                       int2* __restrict__ adj, int E) {
    int i = blockIdx.x * blockDim.x + threadIdx.x;
    if (i < E) {
        int p = atomicAdd(&cursor[dst[i]], 1);
        int2 e;
        e.x = src[i];
        e.y = __float_as_int(ew[i]);
        adj[p] = e;
    }
}

// ---- aggregation: one wave per node, uint2/lane row gathers, 8-deep MLP ----

template <int SELF>
__global__ void agg_k(const uint2* __restrict__ xb2, const int* __restrict__ rowptr,
                      const int2* __restrict__ adj, uint2* __restrict__ aggb2,
                      float* __restrict__ sumew, int N) {
    int wid = (blockIdx.x * blockDim.x + threadIdx.x) >> 6;
    int lane = threadIdx.x & 63;
    if (wid >= N) return;
    int half = lane >> 5;   // 0: even edges, 1: odd edges
    int sl = lane & 31;     // column quad (4 bf16 per lane)
    int lo = rowptr[wid], hi = rowptr[wid + 1];
    float a0 = 0.f, a1 = 0.f, a2 = 0.f, a3 = 0.f, ws = 0.f;
    if (SELF && half == 0) {
        uint2 v = xb2[(size_t)wid * 32 + sl];
        a0 = bf2f(v.x & 0xffffu); a1 = bf2f(v.x >> 16);
        a2 = bf2f(v.y & 0xffffu); a3 = bf2f(v.y >> 16);
    }
    for (int base = lo; base < hi; base += 64) {
        int p = base + lane;
        int sidx = 0; float wv = 0.f;
        if (p < hi) {
            int2 e = adj[p];
            sidx = e.x;
            wv = __int_as_float(e.y);
        }
        ws += wv;
        int cnt = min(hi - base, 64);
        int j = 0;
        for (; j + 16 <= cnt; j += 16) {  // 8 gathers in flight per half
            int ss[8]; float ww[8]; uint2 vv[8];
#pragma unroll
            for (int q = 0; q < 8; ++q) {
                ss[q] = __shfl(sidx, j + 2 * q + half);
                ww[q] = __shfl(wv, j + 2 * q + half);
            }
#pragma unroll
            for (int q = 0; q < 8; ++q) vv[q] = xb2[(size_t)ss[q] * 32 + sl];
#pragma unroll
            for (int q = 0; q < 8; ++q) {
                a0 += ww[q] * bf2f(vv[q].x & 0xffffu); a1 += ww[q] * bf2f(vv[q].x >> 16);
                a2 += ww[q] * bf2f(vv[q].y & 0xffffu); a3 += ww[q] * bf2f(vv[q].y >> 16);
            }
        }
        for (; j + 4 <= cnt; j += 4) {
            int s0 = __shfl(sidx, j + half), s1 = __shfl(sidx, j + 2 + half);
            float w0 = __shfl(wv, j + half), w1 = __shfl(wv, j + 2 + half);
            uint2 v0 = xb2[(size_t)s0 * 32 + sl];
            uint2 v1 = xb2[(size_t)s1 * 32 + sl];
            a0 += w0 * bf2f(v0.x & 0xffffu); a1 += w0 * bf2f(v0.x >> 16);
            a2 += w0 * bf2f(v0.y & 0xffffu); a3 += w0 * bf2f(v0.y >> 16);
            a0 += w1 * bf2f(v1.x & 0xffffu); a1 += w1 * bf2f(v1.x >> 16);
            a2 += w1 * bf2f(v1.y & 0xffffu); a3 += w1 * bf2f(v1.y >> 16);
        }
        for (; j < cnt; j += 2) {
            // phantom odd-tail edge has sidx=0, wv=0 -> harmless
            int s0 = __shfl(sidx, j + half);
            float w0 = __shfl(wv, j + half);
            uint2 v0 = xb2[(size_t)s0 * 32 + sl];
            a0 += w0 * bf2f(v0.x & 0xffffu); a1 += w0 * bf2f(v0.x >> 16);
            a2 += w0 * bf2f(v0.y & 0xffffu); a3 += w0 * bf2f(v0.y >> 16);
        }
    }
    // combine half-waves
    a0 += __shfl_xor(a0, 32);
    a1 += __shfl_xor(a1, 32);
    a2 += __shfl_xor(a2, 32);
    a3 += __shfl_xor(a3, 32);
    if (!SELF) {
        ws += __shfl_xor(ws, 1);
        ws += __shfl_xor(ws, 2);
        ws += __shfl_xor(ws, 4);
        ws += __shfl_xor(ws, 8);
        ws += __shfl_xor(ws, 16);
        ws += __shfl_xor(ws, 32);
        if (lane == 0) sumew[wid] = ws;
    }
    float inv = SELF ? 1.0f / (float)(hi - lo + 1)
                     : 1.0f / fmaxf((float)(hi - lo), 1.0f);
    if (half == 0) {
        uint2 o;
        o.x = f2bf(a0 * inv) | (f2bf(a1 * inv) << 16);
        o.y = f2bf(a2 * inv) | (f2bf(a3 * inv) << 16);
        aggb2[(size_t)wid * 32 + sl] = o;
    }
}

// ---------------- MFMA GEMMs: one wave per 16-row strip ----------------
// A frag: row=lane&15, k=(lane>>4)*8+j ; B frag: col=lane&15, same k
// D: col=lane&15, row=(lane>>4)*4+reg   [m89-verified]

__global__ __launch_bounds__(256) void mm1_k(
    const ushort* __restrict__ aggb, const ushort* __restrict__ Wt,
    const float* __restrict__ bl, const float* __restrict__ sumew,
    const int* __restrict__ rowptr, ushort* __restrict__ x1b, int N) {
    int lane = threadIdx.x & 63;
    int strip = blockIdx.x * 4 + (threadIdx.x >> 6);
    int nstrips = (N + 15) >> 4;
    if (strip >= nstrips) return;
    int row0 = strip << 4;
    int arow = row0 + (lane & 15);
    if (arow >= N) arow = N - 1;
    int kg = (lane >> 4) << 3;
    int bcol = lane & 15;

    bf16x8 af[4];
#pragma unroll
    for (int kc = 0; kc < 4; ++kc)
        af[kc] = *(const bf16x8*)(aggb + (size_t)arow * DF + kc * 32 + kg);

    f32x4 acc[8];
#pragma unroll
    for (int nt = 0; nt < 8; ++nt) {
        f32x4 a = {0.f, 0.f, 0.f, 0.f};
#pragma unroll
        for (int kc = 0; kc < 4; ++kc) {
            bf16x8 bf = *(const bf16x8*)(Wt + (size_t)(nt * 16 + bcol) * DF + kc * 32 + kg);
            a = __builtin_amdgcn_mfma_f32_16x16x32_bf16(af[kc], bf, a, 0, 0, 0);
        }
        acc[nt] = a;
    }

#pragma unroll
    for (int r = 0; r < 4; ++r) {
        int R = row0 + ((lane >> 4) << 2) + r;
        if (R >= N) continue;
        int deg = rowptr[R + 1] - rowptr[R];
        float wb = sumew[R] / fmaxf((float)deg, 1.0f);
#pragma unroll
        for (int nt = 0; nt < 8; ++nt) {
            int col = nt * 16 + bcol;
            x1b[(size_t)R * DF + col] = (ushort)f2bf(acc[nt][r] + bl[col] * wb);
        }
    }
}

__device__ __forceinline__ float gelu_exact(float v) {
    return 0.5f * v * (1.0f + erff(v * 0.70710678118654752440f));
}

__global__ __launch_bounds__(256) void mm2_k(
    const ushort* __restrict__ aggb, const ushort* __restrict__ Wt,
    const float* __restrict__ bl, const float* __restrict__ sumew,
    const int* __restrict__ rowptr, const ushort* __restrict__ x1b,
    const float* __restrict__ gamma, const float* __restrict__ beta,
    float* __restrict__ out, int N) {
    int lane = threadIdx.x & 63;
    int strip = blockIdx.x * 4 + (threadIdx.x >> 6);
    int nstrips = (N + 15) >> 4;
    if (strip >= nstrips) return;
    int row0 = strip << 4;
    int arow = row0 + (lane & 15);
    if (arow >= N) arow = N - 1;
    int kg = (lane >> 4) << 3;
    int bcol = lane & 15;

    bf16x8 af[4];
#pragma unroll
    for (int kc = 0; kc < 4; ++kc)
        af[kc] = *(const bf16x8*)(aggb + (size_t)arow * DF + kc * 32 + kg);

    f32x4 acc[8];
#pragma unroll
    for (int nt = 0; nt < 8; ++nt) {
        f32x4 a = {0.f, 0.f, 0.f, 0.f};
#pragma unroll
        for (int kc = 0; kc < 4; ++kc) {
            bf16x8 bf = *(const bf16x8*)(Wt + (size_t)(nt * 16 + bcol) * DF + kc * 32 + kg);
            a = __builtin_amdgcn_mfma_f32_16x16x32_bf16(af[kc], bf, a, 0, 0, 0);
        }
        acc[nt] = a;
    }

#pragma unroll
    for (int r = 0; r < 4; ++r) {
        int R = row0 + ((lane >> 4) << 2) + r;
        if (R >= N) continue;
        int deg = rowptr[R + 1] - rowptr[R];
        float wb = (sumew[R] + 1.0f) / (float)(deg + 1);
        float pre[8];
        float s = 0.f;
#pragma unroll
        for (int nt = 0; nt < 8; ++nt) {
            int col = nt * 16 + bcol;
            pre[nt] = acc[nt][r] + bl[col] * wb + bf2f(x1b[(size_t)R * DF + col]);
            s += pre[nt];
        }
        s += __shfl_xor(s, 1);
        s += __shfl_xor(s, 2);
        s += __shfl_xor(s, 4);
        s += __shfl_xor(s, 8);
        float mu = s * (1.0f / 128.0f);
        float vs = 0.f;
#pragma unroll
        for (int nt = 0; nt < 8; ++nt) {
            float d = pre[nt] - mu;
            vs += d * d;
        }
        vs += __shfl_xor(vs, 1);
        vs += __shfl_xor(vs, 2);
        vs += __shfl_xor(vs, 4);
        vs += __shfl_xor(vs, 8);
        float rstd = rsqrtf(vs * (1.0f / 128.0f) + 1e-5f);
#pragma unroll
        for (int nt = 0; nt < 8; ++nt) {
            int col = nt * 16 + bcol;
            float y = (pre[nt] - mu) * rstd * gamma[col] + beta[col];
            out[(size_t)R * DF + col] = gelu_exact(y);
        }
    }
}

// ---------------- launch ----------------

extern "C" void kernel_launch(void* const* d_in, const int* in_sizes, int n_in,
                              void* d_out, int out_size, void* d_ws, size_t ws_size,
                              hipStream_t stream) {
    const float* x     = (const float*)d_in[0];
    const int*   ei    = (const int*)d_in[1];
    const float* ew    = (const float*)d_in[2];
    const float* Wl1   = (const float*)d_in[3];
    const float* bl1   = (const float*)d_in[4];
    const float* Wl2   = (const float*)d_in[5];
    const float* bl2   = (const float*)d_in[6];
    const float* gamma = (const float*)d_in[7];
    const float* beta  = (const float*)d_in[8];
    float* out = (float*)d_out;

    int N = in_sizes[0] / DF;
    int E = in_sizes[2];
    const int* src = ei;
    const int* dst = ei + E;

    char* ws = (char*)d_ws;
    size_t off = 0;
    auto alloc = [&](size_t bytes) -> void* {
        void* p = ws + off;
        off += (bytes + 255) & ~(size_t)255;
        return p;
    };
    int histB = (E + EPB - 1) / EPB;
    float*  sumew   = (float*)alloc((size_t)N * 4);
    int*    rowptr  = (int*)alloc((size_t)(N + 1) * 4);
    int*    cursor  = (int*)alloc((size_t)N * 4);
    int*    bhist   = (int*)alloc((size_t)histB * 256 * 4);
    int*    bkoff   = (int*)alloc(1040);
    int*    bsum    = (int*)alloc(1024);
    int*    boff    = (int*)alloc(1024);
    int2*   adj     = (int2*)alloc((size_t)E * 8);
    uint2*  stage   = (uint2*)alloc((size_t)E * 8);
    uint*   xb      = (uint*)alloc((size_t)N * DF * 2);
    uint*   aggb    = (uint*)alloc((size_t)N * DF * 2);
    ushort* x1b     = (ushort*)alloc((size_t)N * DF * 2);
    uint*   Wt1     = (uint*)alloc((size_t)DF * DF * 2);
    uint*   Wt2     = (uint*)alloc((size_t)DF * DF * 2);
    int*    cnt     = (int*)alloc((size_t)N * 4);  // fallback path only

    int nbk = (N + NPB - 1) / NPB;
    int n4 = N * DF / 4;
    int cvtxB = (n4 + 255) / 256;

    if (nbk <= 256) {
        hipLaunchKernelGGL(prep_k, dim3(cvtxB + 64 + histB), dim3(256), 0, stream,
                           x, xb, n4, Wl1, Wl2, Wt1, Wt2, dst, bhist, E, cvtxB);
        hipLaunchKernelGGL(passA_k, dim3(histB), dim3(256), 0, stream,
                           src, dst, ew, bhist, histB, bkoff, stage, E);
        hipLaunchKernelGGL(passB_k, dim3(nbk), dim3(256), 0, stream,
                           stage, bkoff, rowptr, cursor, adj, N, nbk);
    } else {  // generic fallback (not taken for this problem size)
        hipMemsetAsync(cnt, 0, (size_t)N * 4, stream);
        hipLaunchKernelGGL(prep_k, dim3(cvtxB + 64), dim3(256), 0, stream,
                           x, xb, n4, Wl1, Wl2, Wt1, Wt2, dst, bhist, 0, cvtxB);
        int eb = (E + 255) / 256;
        hipLaunchKernelGGL(histn_k, dim3(eb), dim3(256), 0, stream, dst, cnt, E);
        int nb_scan = (N + 1023) / 1024;
        hipLaunchKernelGGL(partial_k, dim3(nb_scan), dim3(256), 0, stream, cnt, bsum, N);
        hipLaunchKernelGGL(scanb_k, dim3(1), dim3(256), 0, stream, bsum, boff, rowptr, nb_scan, N);
        hipLaunchKernelGGL(rowfill_k, dim3(nb_scan), dim3(256), 0, stream, cnt, boff, rowptr, cursor, N);
        hipLaunchKernelGGL(fill_k, dim3(eb), dim3(256), 0, stream, src, dst, ew, cursor, adj, E);
    }

    int nb = (N * 64 + 255) / 256;
    int nstrips = (N + 15) / 16;
    int mb = (nstrips + 3) / 4;

    hipLaunchKernelGGL(agg_k<0>, dim3(nb), dim3(256), 0, stream,
                       (const uint2*)xb, rowptr, adj, (uint2*)aggb, sumew, N);
    hipLaunchKernelGGL(mm1_k, dim3(mb), dim3(256), 0, stream,
                       (const ushort*)aggb, (const ushort*)Wt1, bl1, sumew, rowptr, x1b, N);
    hipLaunchKernelGGL(agg_k<1>, dim3(nb), dim3(256), 0, stream,
                       (const uint2*)x1b, rowptr, adj, (uint2*)aggb, sumew, N);
    hipLaunchKernelGGL(mm2_k, dim3(mb), dim3(256), 0, stream,
                       (const ushort*)aggb, (const ushort*)Wt2, bl2, sumew, rowptr, x1b, gamma, beta, out, N);
}

// Round 12
// 173.079 us; speedup vs baseline: 1.1560x; 1.1560x over previous
//
#include <hip/hip_runtime.h>
#include <math.h>

#define DF 128
#define NPB 256    // nodes per bucket (partition path)
#define EPB 4096   // edges per hist block (prep)
#define EPBA 1024  // edges per passA block (occupancy-tuned)
#define CAP 7168   // passB LDS image capacity (edges)

typedef __attribute__((ext_vector_type(8))) short bf16x8;
typedef __attribute__((ext_vector_type(4))) float f32x4;

__device__ __forceinline__ float bf2f(uint u) {
    union { uint i; float f; } v; v.i = u << 16; return v.f;
}
__device__ __forceinline__ uint f2bf(float f) {  // round-to-nearest-even
    union { float f; uint i; } v; v.f = f;
    return (v.i + 0x7fffu + ((v.i >> 16) & 1u)) >> 16;
}

// ---- fused prep: cvt_x (float4) + cvtW + per-block bucket hist (no atomics, no memset) ----

__global__ void prep_k(const float* __restrict__ x, uint* __restrict__ xb, int n4,
                       const float* __restrict__ W1, const float* __restrict__ W2,
                       uint* __restrict__ Wt1, uint* __restrict__ Wt2,
                       const int* __restrict__ dst, int* __restrict__ bhist, int E,
                       int cvtxB) {
    __shared__ int lh[256];
    int b = blockIdx.x;
    int t = threadIdx.x;
    if (b < cvtxB) {
        int i = b * 256 + t;
        if (i < n4) {
            float4 v = ((const float4*)x)[i];
            uint2 o;
            o.x = f2bf(v.x) | (f2bf(v.y) << 16);
            o.y = f2bf(v.z) | (f2bf(v.w) << 16);
            ((uint2*)xb)[i] = o;
        }
    } else if (b < cvtxB + 64) {
        int i = (b - cvtxB) * 256 + t;  // 0..16383
        const float* W = (i < 8192) ? W1 : W2;
        uint* Wt = (i < 8192) ? Wt1 : Wt2;
        int j = i & 8191;
        int n = j >> 6, kk = j & 63;
        Wt[n * 64 + kk] = f2bf(W[(2 * kk) * DF + n]) | (f2bf(W[(2 * kk + 1) * DF + n]) << 16);
    } else {
        // bucket-level histogram: EPB edges per block, LDS bins, streamed out per-block
        int hb = b - cvtxB - 64;
        int base = hb * EPB;
        lh[t] = 0;
        __syncthreads();
#pragma unroll
        for (int k = 0; k < EPB / 256; ++k) {
            int i = base + k * 256 + t;
            if (i < E) atomicAdd(&lh[dst[i] >> 8], 1);
        }
        __syncthreads();
        bhist[hb * 256 + t] = lh[t];
    }
}

// single block: reduce per-block hists + exclusive scan -> bkoff[257], init gcur
__global__ void bscan_k(const int* __restrict__ bhist, int histB,
                        int* __restrict__ bkoff, int* __restrict__ gcur) {
    int t = threadIdx.x;
    int v = 0;
#pragma unroll 4
    for (int hb = 0; hb < histB; ++hb) v += bhist[hb * 256 + t];
    __shared__ int sm[256];
    sm[t] = v;
    __syncthreads();
    for (int off = 1; off < 256; off <<= 1) {
        int u = (t >= off) ? sm[t - off] : 0;
        __syncthreads();
        sm[t] += u;
        __syncthreads();
    }
    int ex = sm[t] - v;
    bkoff[t] = ex;
    gcur[t] = ex;
    if (t == 255) bkoff[256] = sm[255];
}

// ---------------- partitioned CSR fill ----------------
// Pass A: block-local counting sort of a 1024-edge chunk by dst bucket, write
// per-bucket runs into staging (bucket-major layout). Small chunk -> 782
// blocks (~3/CU) for latency hiding; int lbk avoids byte-write bank conflicts.
__global__ __launch_bounds__(256) void passA_k(
    const int* __restrict__ src, const int* __restrict__ dst,
    const float* __restrict__ ew, int* __restrict__ gcur,
    uint2* __restrict__ stage, int E) {
    __shared__ int lhist[256];
    __shared__ int lscan[256];
    __shared__ int lcur[256];
    __shared__ int gbase[256];
    __shared__ int lbk[EPBA];
    __shared__ uint2 img[EPBA];
    int t = threadIdx.x;
    int base = blockIdx.x * EPBA;
    int cnt = min(EPBA, E - base);
    lhist[t] = 0;
    __syncthreads();
    uint ps[EPBA / 256], pw[EPBA / 256];
    int pb[EPBA / 256];
#pragma unroll
    for (int k = 0; k < EPBA / 256; ++k) {
        int i = base + k * 256 + t;
        pb[k] = -1;
        if (i < E) {
            int d = dst[i];
            int bk = d >> 8;  // NPB=256
            pb[k] = bk;
            ps[k] = (uint)src[i] | ((uint)(d & 255) << 23);
            pw[k] = __float_as_uint(ew[i]);
            atomicAdd(&lhist[bk], 1);
        }
    }
    __syncthreads();
    int v = lhist[t];
    lscan[t] = v;
    __syncthreads();
    for (int off = 1; off < 256; off <<= 1) {
        int u = (t >= off) ? lscan[t - off] : 0;
        __syncthreads();
        lscan[t] += u;
        __syncthreads();
    }
    lcur[t] = lscan[t] - v;  // exclusive prefix
    if (v > 0) gbase[t] = atomicAdd(&gcur[t], v);
    __syncthreads();
#pragma unroll
    for (int k = 0; k < EPBA / 256; ++k) {
        if (pb[k] >= 0) {
            int p = atomicAdd(&lcur[pb[k]], 1);
            img[p] = make_uint2(ps[k], pw[k]);
            lbk[p] = pb[k];
        }
    }
    __syncthreads();
    for (int i = t; i < cnt; i += 256) {
        int bk = lbk[i];
        stage[gbase[bk] + (i - (lscan[bk] - lhist[bk]))] = img[i];
    }
}

// Pass B: one block per bucket. Builds the node-level CSR locally (LDS
// histogram + scan -> rowptr), scatters staged edges into an LDS image,
// copies out coalesced.
__global__ __launch_bounds__(256) void passB_k(
    const uint2* __restrict__ stage, const int* __restrict__ bkoff,
    int* __restrict__ rowptr, int* __restrict__ cursor,
    int2* __restrict__ adj, int N, int nbk) {
    __shared__ int lhist[256];
    __shared__ int lpre[256];
    __shared__ int lcur[256];
    __shared__ uint2 img[CAP];
    int t = threadIdx.x;
    int b = blockIdx.x;
    int nb0 = b * NPB;
    int nn = min(NPB, N - nb0);
    int ebase = bkoff[b];
    int ecnt = bkoff[b + 1] - ebase;
    lhist[t] = 0;
    __syncthreads();
    for (int i = t; i < ecnt; i += 256) {
        uint2 e = stage[ebase + i];
        atomicAdd(&lhist[(e.x >> 23) & 255], 1);
    }
    __syncthreads();
    int v = lhist[t];
    lpre[t] = v;
    __syncthreads();
    for (int off = 1; off < 256; off <<= 1) {
        int u = (t >= off) ? lpre[t - off] : 0;
        __syncthreads();
        lpre[t] += u;
        __syncthreads();
    }
    int myoff = lpre[t] - v;  // exclusive prefix within bucket
    lcur[t] = myoff;
    if (t < nn) {
        rowptr[nb0 + t] = ebase + myoff;
        cursor[nb0 + t] = ebase + myoff;
    }
    if (b == nbk - 1 && t == 0) rowptr[N] = ebase + ecnt;
    __syncthreads();
    if (ecnt <= CAP) {
        for (int i = t; i < ecnt; i += 256) {
            uint2 e = stage[ebase + i];
            int p = atomicAdd(&lcur[(e.x >> 23) & 255], 1);
            img[p] = make_uint2(e.x & 0x7fffffu, e.y);
        }
        __syncthreads();
        for (int i = t; i < ecnt; i += 256) {
            uint2 e = img[i];
            adj[ebase + i] = make_int2((int)e.x, (int)e.y);
        }
    } else {  // statistically unreachable; correctness fallback
        for (int i = t; i < ecnt; i += 256) {
            uint2 e = stage[ebase + i];
            int dl = (e.x >> 23) & 255;
            int p = atomicAdd(&cursor[nb0 + dl], 1);
            adj[p] = make_int2((int)(e.x & 0x7fffffu), (int)e.y);
        }
    }
}

// ---------------- generic fallback path (N > 65536 only) ----------------

__global__ void histn_k(const int* __restrict__ dst, int* __restrict__ cnt, int E) {
    int i = blockIdx.x * blockDim.x + threadIdx.x;
    if (i < E) atomicAdd(&cnt[dst[i]], 1);
}

__global__ void partial_k(const int* __restrict__ cnt, int* __restrict__ bsum, int N) {
    int t = threadIdx.x, b = blockIdx.x;
    int base = b * 1024 + t * 4;
    int s = 0;
    if (base + 4 <= N) {
        int4 v = *(const int4*)(cnt + base);
        s = v.x + v.y + v.z + v.w;
    } else {
        for (int j = 0; j < 4; ++j)
            if (base + j < N) s += cnt[base + j];
    }
    __shared__ int sm[256];
    sm[t] = s;
    __syncthreads();
    for (int off = 128; off > 0; off >>= 1) {
        if (t < off) sm[t] += sm[t + off];
        __syncthreads();
    }
    if (t == 0) bsum[b] = sm[0];
}

__global__ void scanb_k(const int* __restrict__ bsum, int* __restrict__ boff,
                        int* __restrict__ rowptr, int nb, int N) {
    int t = threadIdx.x;
    int v = (t < nb) ? bsum[t] : 0;
    __shared__ int sm[256];
    sm[t] = v;
    __syncthreads();
    for (int off = 1; off < 256; off <<= 1) {
        int u = (t >= off) ? sm[t - off] : 0;
        __syncthreads();
        sm[t] += u;
        __syncthreads();
    }
    if (t < nb) boff[t] = sm[t] - v;
    if (t == 255) rowptr[N] = sm[255];
}

__global__ void rowfill_k(const int* __restrict__ cnt, const int* __restrict__ boff,
                          int* __restrict__ rowptr, int* __restrict__ cursor, int N) {
    int t = threadIdx.x, b = blockIdx.x;
    int base = b * 1024 + t * 4;
    int c0 = 0, c1 = 0, c2 = 0, c3 = 0;
    if (base + 4 <= N) {
        int4 v = *(const int4*)(cnt + base);
        c0 = v.x; c1 = v.y; c2 = v.z; c3 = v.w;
    } else {
        if (base + 0 < N) c0 = cnt[base + 0];
        if (base + 1 < N) c1 = cnt[base + 1];
        if (base + 2 < N) c2 = cnt[base + 2];
        if (base + 3 < N) c3 = cnt[base + 3];
    }
    int s = c0 + c1 + c2 + c3;
    __shared__ int sm[256];
    sm[t] = s;
    __syncthreads();
    for (int off = 1; off < 256; off <<= 1) {
        int u = (t >= off) ? sm[t - off] : 0;
        __syncthreads();
        sm[t] += u;
        __syncthreads();
    }
    int run = boff[b] + sm[t] - s;
    if (base + 0 < N) { rowptr[base + 0] = run; cursor[base + 0] = run; run += c0; }
    if (base + 1 < N) { rowptr[base + 1] = run; cursor[base + 1] = run; run += c1; }
    if (base + 2 < N) { rowptr[base + 2] = run; cursor[base + 2] = run; run += c2; }
    if (base + 3 < N) { rowptr[base + 3] = run; cursor[base + 3] = run; run += c3; }
}

__global__ void fill_k(const int* __restrict__ src, const int* __restrict__ dst,
                       const float* __restrict__ ew, int* __restrict__ cursor,
                       int2* __restrict__ adj, int E) {
    int i = blockIdx.x * blockDim.x + threadIdx.x;
    if (i < E) {
        int p = atomicAdd(&cursor[dst[i]], 1);
        int2 e;
        e.x = src[i];
        e.y = __float_as_int(ew[i]);
        adj[p] = e;
    }
}

// ---- aggregation: one wave per node, uint2/lane row gathers, 8-deep MLP ----

template <int SELF>
__global__ void agg_k(const uint2* __restrict__ xb2, const int* __restrict__ rowptr,
                      const int2* __restrict__ adj, uint2* __restrict__ aggb2,
                      float* __restrict__ sumew, int N) {
    int wid = (blockIdx.x * blockDim.x + threadIdx.x) >> 6;
    int lane = threadIdx.x & 63;
    if (wid >= N) return;
    int half = lane >> 5;   // 0: even edges, 1: odd edges
    int sl = lane & 31;     // column quad (4 bf16 per lane)
    int lo = rowptr[wid], hi = rowptr[wid + 1];
    float a0 = 0.f, a1 = 0.f, a2 = 0.f, a3 = 0.f, ws = 0.f;
    if (SELF && half == 0) {
        uint2 v = xb2[(size_t)wid * 32 + sl];
        a0 = bf2f(v.x & 0xffffu); a1 = bf2f(v.x >> 16);
        a2 = bf2f(v.y & 0xffffu); a3 = bf2f(v.y >> 16);
    }
    for (int base = lo; base < hi; base += 64) {
        int p = base + lane;
        int sidx = 0; float wv = 0.f;
        if (p < hi) {
            int2 e = adj[p];
            sidx = e.x;
            wv = __int_as_float(e.y);
        }
        ws += wv;
        int cnt = min(hi - base, 64);
        int j = 0;
        for (; j + 16 <= cnt; j += 16) {  // 8 gathers in flight per half
            int ss[8]; float ww[8]; uint2 vv[8];
#pragma unroll
            for (int q = 0; q < 8; ++q) {
                ss[q] = __shfl(sidx, j + 2 * q + half);
                ww[q] = __shfl(wv, j + 2 * q + half);
            }
#pragma unroll
            for (int q = 0; q < 8; ++q) vv[q] = xb2[(size_t)ss[q] * 32 + sl];
#pragma unroll
            for (int q = 0; q < 8; ++q) {
                a0 += ww[q] * bf2f(vv[q].x & 0xffffu); a1 += ww[q] * bf2f(vv[q].x >> 16);
                a2 += ww[q] * bf2f(vv[q].y & 0xffffu); a3 += ww[q] * bf2f(vv[q].y >> 16);
            }
        }
        for (; j + 4 <= cnt; j += 4) {
            int s0 = __shfl(sidx, j + half), s1 = __shfl(sidx, j + 2 + half);
            float w0 = __shfl(wv, j + half), w1 = __shfl(wv, j + 2 + half);
            uint2 v0 = xb2[(size_t)s0 * 32 + sl];
            uint2 v1 = xb2[(size_t)s1 * 32 + sl];
            a0 += w0 * bf2f(v0.x & 0xffffu); a1 += w0 * bf2f(v0.x >> 16);
            a2 += w0 * bf2f(v0.y & 0xffffu); a3 += w0 * bf2f(v0.y >> 16);
            a0 += w1 * bf2f(v1.x & 0xffffu); a1 += w1 * bf2f(v1.x >> 16);
            a2 += w1 * bf2f(v1.y & 0xffffu); a3 += w1 * bf2f(v1.y >> 16);
        }
        for (; j < cnt; j += 2) {
            // phantom odd-tail edge has sidx=0, wv=0 -> harmless
            int s0 = __shfl(sidx, j + half);
            float w0 = __shfl(wv, j + half);
            uint2 v0 = xb2[(size_t)s0 * 32 + sl];
            a0 += w0 * bf2f(v0.x & 0xffffu); a1 += w0 * bf2f(v0.x >> 16);
            a2 += w0 * bf2f(v0.y & 0xffffu); a3 += w0 * bf2f(v0.y >> 16);
        }
    }
    // combine half-waves
    a0 += __shfl_xor(a0, 32);
    a1 += __shfl_xor(a1, 32);
    a2 += __shfl_xor(a2, 32);
    a3 += __shfl_xor(a3, 32);
    if (!SELF) {
        ws += __shfl_xor(ws, 1);
        ws += __shfl_xor(ws, 2);
        ws += __shfl_xor(ws, 4);
        ws += __shfl_xor(ws, 8);
        ws += __shfl_xor(ws, 16);
        ws += __shfl_xor(ws, 32);
        if (lane == 0) sumew[wid] = ws;
    }
    float inv = SELF ? 1.0f / (float)(hi - lo + 1)
                     : 1.0f / fmaxf((float)(hi - lo), 1.0f);
    if (half == 0) {
        uint2 o;
        o.x = f2bf(a0 * inv) | (f2bf(a1 * inv) << 16);
        o.y = f2bf(a2 * inv) | (f2bf(a3 * inv) << 16);
        aggb2[(size_t)wid * 32 + sl] = o;
    }
}

// ---------------- MFMA GEMMs: one wave per 16-row strip ----------------
// A frag: row=lane&15, k=(lane>>4)*8+j ; B frag: col=lane&15, same k
// D: col=lane&15, row=(lane>>4)*4+reg   [m89-verified]

__global__ __launch_bounds__(256) void mm1_k(
    const ushort* __restrict__ aggb, const ushort* __restrict__ Wt,
    const float* __restrict__ bl, const float* __restrict__ sumew,
    const int* __restrict__ rowptr, ushort* __restrict__ x1b, int N) {
    int lane = threadIdx.x & 63;
    int strip = blockIdx.x * 4 + (threadIdx.x >> 6);
    int nstrips = (N + 15) >> 4;
    if (strip >= nstrips) return;
    int row0 = strip << 4;
    int arow = row0 + (lane & 15);
    if (arow >= N) arow = N - 1;
    int kg = (lane >> 4) << 3;
    int bcol = lane & 15;

    bf16x8 af[4];
#pragma unroll
    for (int kc = 0; kc < 4; ++kc)
        af[kc] = *(const bf16x8*)(aggb + (size_t)arow * DF + kc * 32 + kg);

    f32x4 acc[8];
#pragma unroll
    for (int nt = 0; nt < 8; ++nt) {
        f32x4 a = {0.f, 0.f, 0.f, 0.f};
#pragma unroll
        for (int kc = 0; kc < 4; ++kc) {
            bf16x8 bf = *(const bf16x8*)(Wt + (size_t)(nt * 16 + bcol) * DF + kc * 32 + kg);
            a = __builtin_amdgcn_mfma_f32_16x16x32_bf16(af[kc], bf, a, 0, 0, 0);
        }
        acc[nt] = a;
    }

#pragma unroll
    for (int r = 0; r < 4; ++r) {
        int R = row0 + ((lane >> 4) << 2) + r;
        if (R >= N) continue;
        int deg = rowptr[R + 1] - rowptr[R];
        float wb = sumew[R] / fmaxf((float)deg, 1.0f);
#pragma unroll
        for (int nt = 0; nt < 8; ++nt) {
            int col = nt * 16 + bcol;
            x1b[(size_t)R * DF + col] = (ushort)f2bf(acc[nt][r] + bl[col] * wb);
        }
    }
}

__device__ __forceinline__ float gelu_exact(float v) {
    return 0.5f * v * (1.0f + erff(v * 0.70710678118654752440f));
}

__global__ __launch_bounds__(256) void mm2_k(
    const ushort* __restrict__ aggb, const ushort* __restrict__ Wt,
    const float* __restrict__ bl, const float* __restrict__ sumew,
    const int* __restrict__ rowptr, const ushort* __restrict__ x1b,
    const float* __restrict__ gamma, const float* __restrict__ beta,
    float* __restrict__ out, int N) {
    int lane = threadIdx.x & 63;
    int strip = blockIdx.x * 4 + (threadIdx.x >> 6);
    int nstrips = (N + 15) >> 4;
    if (strip >= nstrips) return;
    int row0 = strip << 4;
    int arow = row0 + (lane & 15);
    if (arow >= N) arow = N - 1;
    int kg = (lane >> 4) << 3;
    int bcol = lane & 15;

    bf16x8 af[4];
#pragma unroll
    for (int kc = 0; kc < 4; ++kc)
        af[kc] = *(const bf16x8*)(aggb + (size_t)arow * DF + kc * 32 + kg);

    f32x4 acc[8];
#pragma unroll
    for (int nt = 0; nt < 8; ++nt) {
        f32x4 a = {0.f, 0.f, 0.f, 0.f};
#pragma unroll
        for (int kc = 0; kc < 4; ++kc) {
            bf16x8 bf = *(const bf16x8*)(Wt + (size_t)(nt * 16 + bcol) * DF + kc * 32 + kg);
            a = __builtin_amdgcn_mfma_f32_16x16x32_bf16(af[kc], bf, a, 0, 0, 0);
        }
        acc[nt] = a;
    }

#pragma unroll
    for (int r = 0; r < 4; ++r) {
        int R = row0 + ((lane >> 4) << 2) + r;
        if (R >= N) continue;
        int deg = rowptr[R + 1] - rowptr[R];
        float wb = (sumew[R] + 1.0f) / (float)(deg + 1);
        float pre[8];
        float s = 0.f;
#pragma unroll
        for (int nt = 0; nt < 8; ++nt) {
            int col = nt * 16 + bcol;
            pre[nt] = acc[nt][r] + bl[col] * wb + bf2f(x1b[(size_t)R * DF + col]);
            s += pre[nt];
        }
        s += __shfl_xor(s, 1);
        s += __shfl_xor(s, 2);
        s += __shfl_xor(s, 4);
        s += __shfl_xor(s, 8);
        float mu = s * (1.0f / 128.0f);
        float vs = 0.f;
#pragma unroll
        for (int nt = 0; nt < 8; ++nt) {
            float d = pre[nt] - mu;
            vs += d * d;
        }
        vs += __shfl_xor(vs, 1);
        vs += __shfl_xor(vs, 2);
        vs += __shfl_xor(vs, 4);
        vs += __shfl_xor(vs, 8);
        float rstd = rsqrtf(vs * (1.0f / 128.0f) + 1e-5f);
#pragma unroll
        for (int nt = 0; nt < 8; ++nt) {
            int col = nt * 16 + bcol;
            float y = (pre[nt] - mu) * rstd * gamma[col] + beta[col];
            out[(size_t)R * DF + col] = gelu_exact(y);
        }
    }
}

// ---------------- launch ----------------

extern "C" void kernel_launch(void* const* d_in, const int* in_sizes, int n_in,
                              void* d_out, int out_size, void* d_ws, size_t ws_size,
                              hipStream_t stream) {
    const float* x     = (const float*)d_in[0];
    const int*   ei    = (const int*)d_in[1];
    const float* ew    = (const float*)d_in[2];
    const float* Wl1   = (const float*)d_in[3];
    const float* bl1   = (const float*)d_in[4];
    const float* Wl2   = (const float*)d_in[5];
    const float* bl2   = (const float*)d_in[6];
    const float* gamma = (const float*)d_in[7];
    const float* beta  = (const float*)d_in[8];
    float* out = (float*)d_out;

    int N = in_sizes[0] / DF;
    int E = in_sizes[2];
    const int* src = ei;
    const int* dst = ei + E;

    char* ws = (char*)d_ws;
    size_t off = 0;
    auto alloc = [&](size_t bytes) -> void* {
        void* p = ws + off;
        off += (bytes + 255) & ~(size_t)255;
        return p;
    };
    int histB = (E + EPB - 1) / EPB;
    float*  sumew   = (float*)alloc((size_t)N * 4);
    int*    rowptr  = (int*)alloc((size_t)(N + 1) * 4);
    int*    cursor  = (int*)alloc((size_t)N * 4);
    int*    bhist   = (int*)alloc((size_t)histB * 256 * 4);
    int*    bkoff   = (int*)alloc(1040);
    int*    gcur    = (int*)alloc(1024);
    int*    bsum    = (int*)alloc(1024);
    int*    boff    = (int*)alloc(1024);
    int2*   adj     = (int2*)alloc((size_t)E * 8);
    uint2*  stage   = (uint2*)alloc((size_t)E * 8);
    uint*   xb      = (uint*)alloc((size_t)N * DF * 2);
    uint*   aggb    = (uint*)alloc((size_t)N * DF * 2);
    ushort* x1b     = (ushort*)alloc((size_t)N * DF * 2);
    uint*   Wt1     = (uint*)alloc((size_t)DF * DF * 2);
    uint*   Wt2     = (uint*)alloc((size_t)DF * DF * 2);
    int*    cnt     = (int*)alloc((size_t)N * 4);  // fallback path only

    int nbk = (N + NPB - 1) / NPB;
    int n4 = N * DF / 4;
    int cvtxB = (n4 + 255) / 256;

    if (nbk <= 256) {
        hipLaunchKernelGGL(prep_k, dim3(cvtxB + 64 + histB), dim3(256), 0, stream,
                           x, xb, n4, Wl1, Wl2, Wt1, Wt2, dst, bhist, E, cvtxB);
        hipLaunchKernelGGL(bscan_k, dim3(1), dim3(256), 0, stream, bhist, histB, bkoff, gcur);
        int aB = (E + EPBA - 1) / EPBA;
        hipLaunchKernelGGL(passA_k, dim3(aB), dim3(256), 0, stream, src, dst, ew, gcur, stage, E);
        hipLaunchKernelGGL(passB_k, dim3(nbk), dim3(256), 0, stream,
                           stage, bkoff, rowptr, cursor, adj, N, nbk);
    } else {  // generic fallback (not taken for this problem size)
        hipMemsetAsync(cnt, 0, (size_t)N * 4, stream);
        hipLaunchKernelGGL(prep_k, dim3(cvtxB + 64), dim3(256), 0, stream,
                           x, xb, n4, Wl1, Wl2, Wt1, Wt2, dst, bhist, 0, cvtxB);
        int eb = (E + 255) / 256;
        hipLaunchKernelGGL(histn_k, dim3(eb), dim3(256), 0, stream, dst, cnt, E);
        int nb_scan = (N + 1023) / 1024;
        hipLaunchKernelGGL(partial_k, dim3(nb_scan), dim3(256), 0, stream, cnt, bsum, N);
        hipLaunchKernelGGL(scanb_k, dim3(1), dim3(256), 0, stream, bsum, boff, rowptr, nb_scan, N);
        hipLaunchKernelGGL(rowfill_k, dim3(nb_scan), dim3(256), 0, stream, cnt, boff, rowptr, cursor, N);
        hipLaunchKernelGGL(fill_k, dim3(eb), dim3(256), 0, stream, src, dst, ew, cursor, adj, E);
    }

    int nb = (N * 64 + 255) / 256;
    int nstrips = (N + 15) / 16;
    int mb = (nstrips + 3) / 4;

    hipLaunchKernelGGL(agg_k<0>, dim3(nb), dim3(256), 0, stream,
                       (const uint2*)xb, rowptr, adj, (uint2*)aggb, sumew, N);
    hipLaunchKernelGGL(mm1_k, dim3(mb), dim3(256), 0, stream,
                       (const ushort*)aggb, (const ushort*)Wt1, bl1, sumew, rowptr, x1b, N);
    hipLaunchKernelGGL(agg_k<1>, dim3(nb), dim3(256), 0, stream,
                       (const uint2*)x1b, rowptr, adj, (uint2*)aggb, sumew, N);
    hipLaunchKernelGGL(mm2_k, dim3(mb), dim3(256), 0, stream,
                       (const ushort*)aggb, (const ushort*)Wt2, bl2, sumew, rowptr, x1b, gamma, beta, out, N);
}

// Round 13
// 169.484 us; speedup vs baseline: 1.1805x; 1.0212x over previous
//
#include <hip/hip_runtime.h>
#include <math.h>

#define DF 128
#define NPB 256    // nodes per bucket (partition path)
#define EPB 4096   // edges per hist block (prep)
#define EPBA 2048  // edges per passA block (occupancy/run-length balance)
#define CAP 7168   // passB LDS image capacity (edges)

typedef __attribute__((ext_vector_type(8))) short bf16x8;
typedef __attribute__((ext_vector_type(4))) float f32x4;

__device__ __forceinline__ float bf2f(uint u) {
    union { uint i; float f; } v; v.i = u << 16; return v.f;
}
__device__ __forceinline__ uint f2bf(float f) {  // round-to-nearest-even
    union { float f; uint i; } v; v.f = f;
    return (v.i + 0x7fffu + ((v.i >> 16) & 1u)) >> 16;
}

// ---- fused prep: cvt_x (float4) + cvtW + per-block bucket hist (no atomics, no memset) ----

__global__ void prep_k(const float* __restrict__ x, uint* __restrict__ xb, int n4,
                       const float* __restrict__ W1, const float* __restrict__ W2,
                       uint* __restrict__ Wt1, uint* __restrict__ Wt2,
                       const int* __restrict__ dst, int* __restrict__ bhist, int E,
                       int cvtxB) {
    __shared__ int lh[256];
    int b = blockIdx.x;
    int t = threadIdx.x;
    if (b < cvtxB) {
        int i = b * 256 + t;
        if (i < n4) {
            float4 v = ((const float4*)x)[i];
            uint2 o;
            o.x = f2bf(v.x) | (f2bf(v.y) << 16);
            o.y = f2bf(v.z) | (f2bf(v.w) << 16);
            ((uint2*)xb)[i] = o;
        }
    } else if (b < cvtxB + 64) {
        int i = (b - cvtxB) * 256 + t;  // 0..16383
        const float* W = (i < 8192) ? W1 : W2;
        uint* Wt = (i < 8192) ? Wt1 : Wt2;
        int j = i & 8191;
        int n = j >> 6, kk = j & 63;
        Wt[n * 64 + kk] = f2bf(W[(2 * kk) * DF + n]) | (f2bf(W[(2 * kk + 1) * DF + n]) << 16);
    } else {
        // bucket-level histogram: EPB edges per block, LDS bins, streamed out per-block
        int hb = b - cvtxB - 64;
        int base = hb * EPB;
        lh[t] = 0;
        __syncthreads();
#pragma unroll
        for (int k = 0; k < EPB / 256; ++k) {
            int i = base + k * 256 + t;
            if (i < E) atomicAdd(&lh[dst[i] >> 8], 1);
        }
        __syncthreads();
        bhist[hb * 256 + t] = lh[t];
    }
}

// single block: reduce per-block hists + exclusive scan -> bkoff[257], init gcur
__global__ void bscan_k(const int* __restrict__ bhist, int histB,
                        int* __restrict__ bkoff, int* __restrict__ gcur) {
    int t = threadIdx.x;
    int v = 0;
#pragma unroll 4
    for (int hb = 0; hb < histB; ++hb) v += bhist[hb * 256 + t];
    __shared__ int sm[256];
    sm[t] = v;
    __syncthreads();
    for (int off = 1; off < 256; off <<= 1) {
        int u = (t >= off) ? sm[t - off] : 0;
        __syncthreads();
        sm[t] += u;
        __syncthreads();
    }
    int ex = sm[t] - v;
    bkoff[t] = ex;
    gcur[t] = ex;
    if (t == 255) bkoff[256] = sm[255];
}

// ---------------- partitioned CSR fill ----------------
// Pass A: block-local counting sort of a 2048-edge chunk by dst bucket, write
// per-bucket runs (~10 edges = 84B) into staging (bucket-major layout).
__global__ __launch_bounds__(256) void passA_k(
    const int* __restrict__ src, const int* __restrict__ dst,
    const float* __restrict__ ew, int* __restrict__ gcur,
    uint2* __restrict__ stage, int E) {
    __shared__ int lhist[256];
    __shared__ int lscan[256];
    __shared__ int lcur[256];
    __shared__ int gbase[256];
    __shared__ int lbk[EPBA];
    __shared__ uint2 img[EPBA];
    int t = threadIdx.x;
    int base = blockIdx.x * EPBA;
    int cnt = min(EPBA, E - base);
    lhist[t] = 0;
    __syncthreads();
    uint ps[EPBA / 256], pw[EPBA / 256];
    int pb[EPBA / 256];
#pragma unroll
    for (int k = 0; k < EPBA / 256; ++k) {
        int i = base + k * 256 + t;
        pb[k] = -1;
        if (i < E) {
            int d = dst[i];
            int bk = d >> 8;  // NPB=256
            pb[k] = bk;
            ps[k] = (uint)src[i] | ((uint)(d & 255) << 23);
            pw[k] = __float_as_uint(ew[i]);
            atomicAdd(&lhist[bk], 1);
        }
    }
    __syncthreads();
    int v = lhist[t];
    lscan[t] = v;
    __syncthreads();
    for (int off = 1; off < 256; off <<= 1) {
        int u = (t >= off) ? lscan[t - off] : 0;
        __syncthreads();
        lscan[t] += u;
        __syncthreads();
    }
    lcur[t] = lscan[t] - v;  // exclusive prefix
    if (v > 0) gbase[t] = atomicAdd(&gcur[t], v);
    __syncthreads();
#pragma unroll
    for (int k = 0; k < EPBA / 256; ++k) {
        if (pb[k] >= 0) {
            int p = atomicAdd(&lcur[pb[k]], 1);
            img[p] = make_uint2(ps[k], pw[k]);
            lbk[p] = pb[k];
        }
    }
    __syncthreads();
    for (int i = t; i < cnt; i += 256) {
        int bk = lbk[i];
        stage[gbase[bk] + (i - (lscan[bk] - lhist[bk]))] = img[i];
    }
}

// Pass B: one block per bucket. Builds the node-level CSR locally (LDS
// histogram + scan -> rowptr), scatters staged edges into an LDS image,
// copies out coalesced.
__global__ __launch_bounds__(256) void passB_k(
    const uint2* __restrict__ stage, const int* __restrict__ bkoff,
    int* __restrict__ rowptr, int* __restrict__ cursor,
    int2* __restrict__ adj, int N, int nbk) {
    __shared__ int lhist[256];
    __shared__ int lpre[256];
    __shared__ int lcur[256];
    __shared__ uint2 img[CAP];
    int t = threadIdx.x;
    int b = blockIdx.x;
    int nb0 = b * NPB;
    int nn = min(NPB, N - nb0);
    int ebase = bkoff[b];
    int ecnt = bkoff[b + 1] - ebase;
    lhist[t] = 0;
    __syncthreads();
    for (int i = t; i < ecnt; i += 256) {
        uint2 e = stage[ebase + i];
        atomicAdd(&lhist[(e.x >> 23) & 255], 1);
    }
    __syncthreads();
    int v = lhist[t];
    lpre[t] = v;
    __syncthreads();
    for (int off = 1; off < 256; off <<= 1) {
        int u = (t >= off) ? lpre[t - off] : 0;
        __syncthreads();
        lpre[t] += u;
        __syncthreads();
    }
    int myoff = lpre[t] - v;  // exclusive prefix within bucket
    lcur[t] = myoff;
    if (t < nn) {
        rowptr[nb0 + t] = ebase + myoff;
        cursor[nb0 + t] = ebase + myoff;
    }
    if (b == nbk - 1 && t == 0) rowptr[N] = ebase + ecnt;
    __syncthreads();
    if (ecnt <= CAP) {
        for (int i = t; i < ecnt; i += 256) {
            uint2 e = stage[ebase + i];
            int p = atomicAdd(&lcur[(e.x >> 23) & 255], 1);
            img[p] = make_uint2(e.x & 0x7fffffu, e.y);
        }
        __syncthreads();
        for (int i = t; i < ecnt; i += 256) {
            uint2 e = img[i];
            adj[ebase + i] = make_int2((int)e.x, (int)e.y);
        }
    } else {  // statistically unreachable; correctness fallback
        for (int i = t; i < ecnt; i += 256) {
            uint2 e = stage[ebase + i];
            int dl = (e.x >> 23) & 255;
            int p = atomicAdd(&cursor[nb0 + dl], 1);
            adj[p] = make_int2((int)(e.x & 0x7fffffu), (int)e.y);
        }
    }
}

// ---------------- generic fallback path (N > 65536 only) ----------------

__global__ void histn_k(const int* __restrict__ dst, int* __restrict__ cnt, int E) {
    int i = blockIdx.x * blockDim.x + threadIdx.x;
    if (i < E) atomicAdd(&cnt[dst[i]], 1);
}

__global__ void partial_k(const int* __restrict__ cnt, int* __restrict__ bsum, int N) {
    int t = threadIdx.x, b = blockIdx.x;
    int base = b * 1024 + t * 4;
    int s = 0;
    if (base + 4 <= N) {
        int4 v = *(const int4*)(cnt + base);
        s = v.x + v.y + v.z + v.w;
    } else {
        for (int j = 0; j < 4; ++j)
            if (base + j < N) s += cnt[base + j];
    }
    __shared__ int sm[256];
    sm[t] = s;
    __syncthreads();
    for (int off = 128; off > 0; off >>= 1) {
        if (t < off) sm[t] += sm[t + off];
        __syncthreads();
    }
    if (t == 0) bsum[b] = sm[0];
}

__global__ void scanb_k(const int* __restrict__ bsum, int* __restrict__ boff,
                        int* __restrict__ rowptr, int nb, int N) {
    int t = threadIdx.x;
    int v = (t < nb) ? bsum[t] : 0;
    __shared__ int sm[256];
    sm[t] = v;
    __syncthreads();
    for (int off = 1; off < 256; off <<= 1) {
        int u = (t >= off) ? sm[t - off] : 0;
        __syncthreads();
        sm[t] += u;
        __syncthreads();
    }
    if (t < nb) boff[t] = sm[t] - v;
    if (t == 255) rowptr[N] = sm[255];
}

__global__ void rowfill_k(const int* __restrict__ cnt, const int* __restrict__ boff,
                          int* __restrict__ rowptr, int* __restrict__ cursor, int N) {
    int t = threadIdx.x, b = blockIdx.x;
    int base = b * 1024 + t * 4;
    int c0 = 0, c1 = 0, c2 = 0, c3 = 0;
    if (base + 4 <= N) {
        int4 v = *(const int4*)(cnt + base);
        c0 = v.x; c1 = v.y; c2 = v.z; c3 = v.w;
    } else {
        if (base + 0 < N) c0 = cnt[base + 0];
        if (base + 1 < N) c1 = cnt[base + 1];
        if (base + 2 < N) c2 = cnt[base + 2];
        if (base + 3 < N) c3 = cnt[base + 3];
    }
    int s = c0 + c1 + c2 + c3;
    __shared__ int sm[256];
    sm[t] = s;
    __syncthreads();
    for (int off = 1; off < 256; off <<= 1) {
        int u = (t >= off) ? sm[t - off] : 0;
        __syncthreads();
        sm[t] += u;
        __syncthreads();
    }
    int run = boff[b] + sm[t] - s;
    if (base + 0 < N) { rowptr[base + 0] = run; cursor[base + 0] = run; run += c0; }
    if (base + 1 < N) { rowptr[base + 1] = run; cursor[base + 1] = run; run += c1; }
    if (base + 2 < N) { rowptr[base + 2] = run; cursor[base + 2] = run; run += c2; }
    if (base + 3 < N) { rowptr[base + 3] = run; cursor[base + 3] = run; run += c3; }
}

__global__ void fill_k(const int* __restrict__ src, const int* __restrict__ dst,
                       const float* __restrict__ ew, int* __restrict__ cursor,
                       int2* __restrict__ adj, int E) {
    int i = blockIdx.x * blockDim.x + threadIdx.x;
    if (i < E) {
        int p = atomicAdd(&cursor[dst[i]], 1);
        int2 e;
        e.x = src[i];
        e.y = __float_as_int(ew[i]);
        adj[p] = e;
    }
}

// ---- aggregation: one wave per node, uint4/lane (16 lanes per row, 4 rows/load) ----

template <int SELF>
__global__ void agg_k(const uint4* __restrict__ xb4, const int* __restrict__ rowptr,
                      const int2* __restrict__ adj, uint4* __restrict__ aggb4,
                      float* __restrict__ sumew, int N) {
    int wid = (blockIdx.x * blockDim.x + threadIdx.x) >> 6;
    int lane = threadIdx.x & 63;
    if (wid >= N) return;
    int g = lane >> 4;      // edge-slot group 0..3
    int c = lane & 15;      // column oct (8 bf16 per lane)
    int lo = rowptr[wid], hi = rowptr[wid + 1];
    float a0 = 0.f, a1 = 0.f, a2 = 0.f, a3 = 0.f;
    float a4 = 0.f, a5 = 0.f, a6 = 0.f, a7 = 0.f, ws = 0.f;
    if (SELF && g == 0) {
        uint4 v = xb4[(size_t)wid * 16 + c];
        a0 = bf2f(v.x & 0xffffu); a1 = bf2f(v.x >> 16);
        a2 = bf2f(v.y & 0xffffu); a3 = bf2f(v.y >> 16);
        a4 = bf2f(v.z & 0xffffu); a5 = bf2f(v.z >> 16);
        a6 = bf2f(v.w & 0xffffu); a7 = bf2f(v.w >> 16);
    }
#define FMA8(V, W)                                                     \
    do {                                                               \
        a0 += (W) * bf2f((V).x & 0xffffu); a1 += (W) * bf2f((V).x >> 16); \
        a2 += (W) * bf2f((V).y & 0xffffu); a3 += (W) * bf2f((V).y >> 16); \
        a4 += (W) * bf2f((V).z & 0xffffu); a5 += (W) * bf2f((V).z >> 16); \
        a6 += (W) * bf2f((V).w & 0xffffu); a7 += (W) * bf2f((V).w >> 16); \
    } while (0)
    for (int base = lo; base < hi; base += 64) {
        int p = base + lane;
        int sidx = 0; float wv = 0.f;
        if (p < hi) {
            int2 e = adj[p];
            sidx = e.x;
            wv = __int_as_float(e.y);
        }
        ws += wv;
        int cnt = min(hi - base, 64);
        int j = 0;
        for (; j + 16 <= cnt; j += 16) {  // 4 rows in flight per group
            int s0 = __shfl(sidx, j + g),      s1 = __shfl(sidx, j + 4 + g);
            int s2 = __shfl(sidx, j + 8 + g),  s3 = __shfl(sidx, j + 12 + g);
            float w0 = __shfl(wv, j + g),      w1 = __shfl(wv, j + 4 + g);
            float w2 = __shfl(wv, j + 8 + g),  w3 = __shfl(wv, j + 12 + g);
            uint4 v0 = xb4[(size_t)s0 * 16 + c];
            uint4 v1 = xb4[(size_t)s1 * 16 + c];
            uint4 v2 = xb4[(size_t)s2 * 16 + c];
            uint4 v3 = xb4[(size_t)s3 * 16 + c];
            FMA8(v0, w0); FMA8(v1, w1); FMA8(v2, w2); FMA8(v3, w3);
        }
        for (; j < cnt; j += 4) {
            // phantom slots (j+g >= cnt) carry sidx=0, wv=0 -> harmless
            int s0 = __shfl(sidx, j + g);
            float w0 = __shfl(wv, j + g);
            uint4 v0 = xb4[(size_t)s0 * 16 + c];
            FMA8(v0, w0);
        }
    }
#undef FMA8
    // combine the 4 edge-slot groups
    a0 += __shfl_xor(a0, 16); a0 += __shfl_xor(a0, 32);
    a1 += __shfl_xor(a1, 16); a1 += __shfl_xor(a1, 32);
    a2 += __shfl_xor(a2, 16); a2 += __shfl_xor(a2, 32);
    a3 += __shfl_xor(a3, 16); a3 += __shfl_xor(a3, 32);
    a4 += __shfl_xor(a4, 16); a4 += __shfl_xor(a4, 32);
    a5 += __shfl_xor(a5, 16); a5 += __shfl_xor(a5, 32);
    a6 += __shfl_xor(a6, 16); a6 += __shfl_xor(a6, 32);
    a7 += __shfl_xor(a7, 16); a7 += __shfl_xor(a7, 32);
    if (!SELF) {
        ws += __shfl_xor(ws, 1);
        ws += __shfl_xor(ws, 2);
        ws += __shfl_xor(ws, 4);
        ws += __shfl_xor(ws, 8);
        ws += __shfl_xor(ws, 16);
        ws += __shfl_xor(ws, 32);
        if (lane == 0) sumew[wid] = ws;
    }
    float inv = SELF ? 1.0f / (float)(hi - lo + 1)
                     : 1.0f / fmaxf((float)(hi - lo), 1.0f);
    if (g == 0) {
        uint4 o;
        o.x = f2bf(a0 * inv) | (f2bf(a1 * inv) << 16);
        o.y = f2bf(a2 * inv) | (f2bf(a3 * inv) << 16);
        o.z = f2bf(a4 * inv) | (f2bf(a5 * inv) << 16);
        o.w = f2bf(a6 * inv) | (f2bf(a7 * inv) << 16);
        aggb4[(size_t)wid * 16 + c] = o;
    }
}

// ---------------- MFMA GEMMs: one wave per 16-row strip ----------------
// A frag: row=lane&15, k=(lane>>4)*8+j ; B frag: col=lane&15, same k
// D: col=lane&15, row=(lane>>4)*4+reg   [m89-verified]

__global__ __launch_bounds__(256) void mm1_k(
    const ushort* __restrict__ aggb, const ushort* __restrict__ Wt,
    const float* __restrict__ bl, const float* __restrict__ sumew,
    const int* __restrict__ rowptr, ushort* __restrict__ x1b, int N) {
    int lane = threadIdx.x & 63;
    int strip = blockIdx.x * 4 + (threadIdx.x >> 6);
    int nstrips = (N + 15) >> 4;
    if (strip >= nstrips) return;
    int row0 = strip << 4;
    int arow = row0 + (lane & 15);
    if (arow >= N) arow = N - 1;
    int kg = (lane >> 4) << 3;
    int bcol = lane & 15;

    bf16x8 af[4];
#pragma unroll
    for (int kc = 0; kc < 4; ++kc)
        af[kc] = *(const bf16x8*)(aggb + (size_t)arow * DF + kc * 32 + kg);

    f32x4 acc[8];
#pragma unroll
    for (int nt = 0; nt < 8; ++nt) {
        f32x4 a = {0.f, 0.f, 0.f, 0.f};
#pragma unroll
        for (int kc = 0; kc < 4; ++kc) {
            bf16x8 bf = *(const bf16x8*)(Wt + (size_t)(nt * 16 + bcol) * DF + kc * 32 + kg);
            a = __builtin_amdgcn_mfma_f32_16x16x32_bf16(af[kc], bf, a, 0, 0, 0);
        }
        acc[nt] = a;
    }

#pragma unroll
    for (int r = 0; r < 4; ++r) {
        int R = row0 + ((lane >> 4) << 2) + r;
        if (R >= N) continue;
        int deg = rowptr[R + 1] - rowptr[R];
        float wb = sumew[R] / fmaxf((float)deg, 1.0f);
#pragma unroll
        for (int nt = 0; nt < 8; ++nt) {
            int col = nt * 16 + bcol;
            x1b[(size_t)R * DF + col] = (ushort)f2bf(acc[nt][r] + bl[col] * wb);
        }
    }
}

__device__ __forceinline__ float gelu_exact(float v) {
    return 0.5f * v * (1.0f + erff(v * 0.70710678118654752440f));
}

__global__ __launch_bounds__(256) void mm2_k(
    const ushort* __restrict__ aggb, const ushort* __restrict__ Wt,
    const float* __restrict__ bl, const float* __restrict__ sumew,
    const int* __restrict__ rowptr, const ushort* __restrict__ x1b,
    const float* __restrict__ gamma, const float* __restrict__ beta,
    float* __restrict__ out, int N) {
    int lane = threadIdx.x & 63;
    int strip = blockIdx.x * 4 + (threadIdx.x >> 6);
    int nstrips = (N + 15) >> 4;
    if (strip >= nstrips) return;
    int row0 = strip << 4;
    int arow = row0 + (lane & 15);
    if (arow >= N) arow = N - 1;
    int kg = (lane >> 4) << 3;
    int bcol = lane & 15;

    bf16x8 af[4];
#pragma unroll
    for (int kc = 0; kc < 4; ++kc)
        af[kc] = *(const bf16x8*)(aggb + (size_t)arow * DF + kc * 32 + kg);

    f32x4 acc[8];
#pragma unroll
    for (int nt = 0; nt < 8; ++nt) {
        f32x4 a = {0.f, 0.f, 0.f, 0.f};
#pragma unroll
        for (int kc = 0; kc < 4; ++kc) {
            bf16x8 bf = *(const bf16x8*)(Wt + (size_t)(nt * 16 + bcol) * DF + kc * 32 + kg);
            a = __builtin_amdgcn_mfma_f32_16x16x32_bf16(af[kc], bf, a, 0, 0, 0);
        }
        acc[nt] = a;
    }

#pragma unroll
    for (int r = 0; r < 4; ++r) {
        int R = row0 + ((lane >> 4) << 2) + r;
        if (R >= N) continue;
        int deg = rowptr[R + 1] - rowptr[R];
        float wb = (sumew[R] + 1.0f) / (float)(deg + 1);
        float pre[8];
        float s = 0.f;
#pragma unroll
        for (int nt = 0; nt < 8; ++nt) {
            int col = nt * 16 + bcol;
            pre[nt] = acc[nt][r] + bl[col] * wb + bf2f(x1b[(size_t)R * DF + col]);
            s += pre[nt];
        }
        s += __shfl_xor(s, 1);
        s += __shfl_xor(s, 2);
        s += __shfl_xor(s, 4);
        s += __shfl_xor(s, 8);
        float mu = s * (1.0f / 128.0f);
        float vs = 0.f;
#pragma unroll
        for (int nt = 0; nt < 8; ++nt) {
            float d = pre[nt] - mu;
            vs += d * d;
        }
        vs += __shfl_xor(vs, 1);
        vs += __shfl_xor(vs, 2);
        vs += __shfl_xor(vs, 4);
        vs += __shfl_xor(vs, 8);
        float rstd = rsqrtf(vs * (1.0f / 128.0f) + 1e-5f);
#pragma unroll
        for (int nt = 0; nt < 8; ++nt) {
            int col = nt * 16 + bcol;
            float y = (pre[nt] - mu) * rstd * gamma[col] + beta[col];
            out[(size_t)R * DF + col] = gelu_exact(y);
        }
    }
}

// ---------------- launch ----------------

extern "C" void kernel_launch(void* const* d_in, const int* in_sizes, int n_in,
                              void* d_out, int out_size, void* d_ws, size_t ws_size,
                              hipStream_t stream) {
    const float* x     = (const float*)d_in[0];
    const int*   ei    = (const int*)d_in[1];
    const float* ew    = (const float*)d_in[2];
    const float* Wl1   = (const float*)d_in[3];
    const float* bl1   = (const float*)d_in[4];
    const float* Wl2   = (const float*)d_in[5];
    const float* bl2   = (const float*)d_in[6];
    const float* gamma = (const float*)d_in[7];
    const float* beta  = (const float*)d_in[8];
    float* out = (float*)d_out;

    int N = in_sizes[0] / DF;
    int E = in_sizes[2];
    const int* src = ei;
    const int* dst = ei + E;

    char* ws = (char*)d_ws;
    size_t off = 0;
    auto alloc = [&](size_t bytes) -> void* {
        void* p = ws + off;
        off += (bytes + 255) & ~(size_t)255;
        return p;
    };
    int histB = (E + EPB - 1) / EPB;
    float*  sumew   = (float*)alloc((size_t)N * 4);
    int*    rowptr  = (int*)alloc((size_t)(N + 1) * 4);
    int*    cursor  = (int*)alloc((size_t)N * 4);
    int*    bhist   = (int*)alloc((size_t)histB * 256 * 4);
    int*    bkoff   = (int*)alloc(1040);
    int*    gcur    = (int*)alloc(1024);
    int*    bsum    = (int*)alloc(1024);
    int*    boff    = (int*)alloc(1024);
    int2*   adj     = (int2*)alloc((size_t)E * 8);
    uint2*  stage   = (uint2*)alloc((size_t)E * 8);
    uint*   xb      = (uint*)alloc((size_t)N * DF * 2);
    uint*   aggb    = (uint*)alloc((size_t)N * DF * 2);
    ushort* x1b     = (ushort*)alloc((size_t)N * DF * 2);
    uint*   Wt1     = (uint*)alloc((size_t)DF * DF * 2);
    uint*   Wt2     = (uint*)alloc((size_t)DF * DF * 2);
    int*    cnt     = (int*)alloc((size_t)N * 4);  // fallback path only

    int nbk = (N + NPB - 1) / NPB;
    int n4 = N * DF / 4;
    int cvtxB = (n4 + 255) / 256;

    if (nbk <= 256) {
        hipLaunchKernelGGL(prep_k, dim3(cvtxB + 64 + histB), dim3(256), 0, stream,
                           x, xb, n4, Wl1, Wl2, Wt1, Wt2, dst, bhist, E, cvtxB);
        hipLaunchKernelGGL(bscan_k, dim3(1), dim3(256), 0, stream, bhist, histB, bkoff, gcur);
        int aB = (E + EPBA - 1) / EPBA;
        hipLaunchKernelGGL(passA_k, dim3(aB), dim3(256), 0, stream, src, dst, ew, gcur, stage, E);
        hipLaunchKernelGGL(passB_k, dim3(nbk), dim3(256), 0, stream,
                           stage, bkoff, rowptr, cursor, adj, N, nbk);
    } else {  // generic fallback (not taken for this problem size)
        hipMemsetAsync(cnt, 0, (size_t)N * 4, stream);
        hipLaunchKernelGGL(prep_k, dim3(cvtxB + 64), dim3(256), 0, stream,
                           x, xb, n4, Wl1, Wl2, Wt1, Wt2, dst, bhist, 0, cvtxB);
        int eb = (E + 255) / 256;
        hipLaunchKernelGGL(histn_k, dim3(eb), dim3(256), 0, stream, dst, cnt, E);
        int nb_scan = (N + 1023) / 1024;
        hipLaunchKernelGGL(partial_k, dim3(nb_scan), dim3(256), 0, stream, cnt, bsum, N);
        hipLaunchKernelGGL(scanb_k, dim3(1), dim3(256), 0, stream, bsum, boff, rowptr, nb_scan, N);
        hipLaunchKernelGGL(rowfill_k, dim3(nb_scan), dim3(256), 0, stream, cnt, boff, rowptr, cursor, N);
        hipLaunchKernelGGL(fill_k, dim3(eb), dim3(256), 0, stream, src, dst, ew, cursor, adj, E);
    }

    int nb = (N * 64 + 255) / 256;
    int nstrips = (N + 15) / 16;
    int mb = (nstrips + 3) / 4;

    hipLaunchKernelGGL(agg_k<0>, dim3(nb), dim3(256), 0, stream,
                       (const uint4*)xb, rowptr, adj, (uint4*)aggb, sumew, N);
    hipLaunchKernelGGL(mm1_k, dim3(mb), dim3(256), 0, stream,
                       (const ushort*)aggb, (const ushort*)Wt1, bl1, sumew, rowptr, x1b, N);
    hipLaunchKernelGGL(agg_k<1>, dim3(nb), dim3(256), 0, stream,
                       (const uint4*)x1b, rowptr, adj, (uint4*)aggb, sumew, N);
    hipLaunchKernelGGL(mm2_k, dim3(mb), dim3(256), 0, stream,
                       (const ushort*)aggb, (const ushort*)Wt2, bl2, sumew, rowptr, x1b, gamma, beta, out, N);
}

// Round 15
// 167.686 us; speedup vs baseline: 1.1931x; 1.0107x over previous
//
#include <hip/hip_runtime.h>
#include <math.h>

#define DF 128
#define NPB 256    // nodes per bucket (partition path)
#define EPB 4096   // edges per hist block (prep)
#define EPBA 2048  // edges per passA block
#define CAP 7168   // passB LDS image capacity (edges)

typedef __attribute__((ext_vector_type(8))) short bf16x8;
typedef __attribute__((ext_vector_type(4))) float f32x4;

__device__ __forceinline__ float bf2f(uint u) {
    union { uint i; float f; } v; v.i = u << 16; return v.f;
}
__device__ __forceinline__ uint f2bf(float f) {  // round-to-nearest-even
    union { float f; uint i; } v; v.f = f;
    return (v.i + 0x7fffu + ((v.i >> 16) & 1u)) >> 16;
}

// ---- fused prep: cvt_x (float4) + cvtW + per-block bucket hist ----

__global__ void prep_k(const float* __restrict__ x, uint* __restrict__ xb, int n4,
                       const float* __restrict__ W1, const float* __restrict__ W2,
                       uint* __restrict__ Wt1, uint* __restrict__ Wt2,
                       const int* __restrict__ dst, int* __restrict__ bhist, int E,
                       int cvtxB) {
    __shared__ int lh[256];
    int b = blockIdx.x;
    int t = threadIdx.x;
    if (b < cvtxB) {
        int i = b * 256 + t;
        if (i < n4) {
            float4 v = ((const float4*)x)[i];
            uint2 o;
            o.x = f2bf(v.x) | (f2bf(v.y) << 16);
            o.y = f2bf(v.z) | (f2bf(v.w) << 16);
            ((uint2*)xb)[i] = o;
        }
    } else if (b < cvtxB + 64) {
        int i = (b - cvtxB) * 256 + t;  // 0..16383
        const float* W = (i < 8192) ? W1 : W2;
        uint* Wt = (i < 8192) ? Wt1 : Wt2;
        int j = i & 8191;
        int n = j >> 6, kk = j & 63;
        Wt[n * 64 + kk] = f2bf(W[(2 * kk) * DF + n]) | (f2bf(W[(2 * kk + 1) * DF + n]) << 16);
    } else {
        int hb = b - cvtxB - 64;
        int base = hb * EPB;
        lh[t] = 0;
        __syncthreads();
#pragma unroll
        for (int k = 0; k < EPB / 256; ++k) {
            int i = base + k * 256 + t;
            if (i < E) atomicAdd(&lh[dst[i] >> 8], 1);
        }
        __syncthreads();
        bhist[hb * 256 + t] = lh[t];
    }
}

// single block: reduce per-block hists + exclusive scan -> bkoff[257], init gcur
__global__ void bscan_k(const int* __restrict__ bhist, int histB,
                        int* __restrict__ bkoff, int* __restrict__ gcur) {
    int t = threadIdx.x;
    int v = 0;
#pragma unroll 4
    for (int hb = 0; hb < histB; ++hb) v += bhist[hb * 256 + t];
    __shared__ int sm[256];
    sm[t] = v;
    __syncthreads();
    for (int off = 1; off < 256; off <<= 1) {
        int u = (t >= off) ? sm[t - off] : 0;
        __syncthreads();
        sm[t] += u;
        __syncthreads();
    }
    int ex = sm[t] - v;
    bkoff[t] = ex;
    gcur[t] = ex;
    if (t == 255) bkoff[256] = sm[255];
}

// ---------------- partitioned CSR fill ----------------

__global__ __launch_bounds__(256) void passA_k(
    const int* __restrict__ src, const int* __restrict__ dst,
    const float* __restrict__ ew, int* __restrict__ gcur,
    uint2* __restrict__ stage, int E) {
    __shared__ int lhist[256];
    __shared__ int lscan[256];
    __shared__ int lcur[256];
    __shared__ int gbase[256];
    __shared__ int lbk[EPBA];
    __shared__ uint2 img[EPBA];
    int t = threadIdx.x;
    int base = blockIdx.x * EPBA;
    int cnt = min(EPBA, E - base);
    lhist[t] = 0;
    __syncthreads();
    uint ps[EPBA / 256], pw[EPBA / 256];
    int pb[EPBA / 256];
#pragma unroll
    for (int k = 0; k < EPBA / 256; ++k) {
        int i = base + k * 256 + t;
        pb[k] = -1;
        if (i < E) {
            int d = dst[i];
            int bk = d >> 8;  // NPB=256
            pb[k] = bk;
            ps[k] = (uint)src[i] | ((uint)(d & 255) << 23);
            pw[k] = __float_as_uint(ew[i]);
            atomicAdd(&lhist[bk], 1);
        }
    }
    __syncthreads();
    int v = lhist[t];
    lscan[t] = v;
    __syncthreads();
    for (int off = 1; off < 256; off <<= 1) {
        int u = (t >= off) ? lscan[t - off] : 0;
        __syncthreads();
        lscan[t] += u;
        __syncthreads();
    }
    lcur[t] = lscan[t] - v;
    if (v > 0) gbase[t] = atomicAdd(&gcur[t], v);
    __syncthreads();
#pragma unroll
    for (int k = 0; k < EPBA / 256; ++k) {
        if (pb[k] >= 0) {
            int p = atomicAdd(&lcur[pb[k]], 1);
            img[p] = make_uint2(ps[k], pw[k]);
            lbk[p] = pb[k];
        }
    }
    __syncthreads();
    for (int i = t; i < cnt; i += 256) {
        int bk = lbk[i];
        stage[gbase[bk] + (i - (lscan[bk] - lhist[bk]))] = img[i];
    }
}

__global__ __launch_bounds__(256) void passB_k(
    const uint2* __restrict__ stage, const int* __restrict__ bkoff,
    int* __restrict__ rowptr, int* __restrict__ cursor,
    int2* __restrict__ adj, int N, int nbk) {
    __shared__ int lhist[256];
    __shared__ int lpre[256];
    __shared__ int lcur[256];
    __shared__ uint2 img[CAP];
    int t = threadIdx.x;
    int b = blockIdx.x;
    int nb0 = b * NPB;
    int nn = min(NPB, N - nb0);
    int ebase = bkoff[b];
    int ecnt = bkoff[b + 1] - ebase;
    lhist[t] = 0;
    __syncthreads();
    for (int i = t; i < ecnt; i += 256) {
        uint2 e = stage[ebase + i];
        atomicAdd(&lhist[(e.x >> 23) & 255], 1);
    }
    __syncthreads();
    int v = lhist[t];
    lpre[t] = v;
    __syncthreads();
    for (int off = 1; off < 256; off <<= 1) {
        int u = (t >= off) ? lpre[t - off] : 0;
        __syncthreads();
        lpre[t] += u;
        __syncthreads();
    }
    int myoff = lpre[t] - v;
    lcur[t] = myoff;
    if (t < nn) {
        rowptr[nb0 + t] = ebase + myoff;
        cursor[nb0 + t] = ebase + myoff;
    }
    if (b == nbk - 1 && t == 0) rowptr[N] = ebase + ecnt;
    __syncthreads();
    if (ecnt <= CAP) {
        for (int i = t; i < ecnt; i += 256) {
            uint2 e = stage[ebase + i];
            int p = atomicAdd(&lcur[(e.x >> 23) & 255], 1);
            img[p] = make_uint2(e.x & 0x7fffffu, e.y);
        }
        __syncthreads();
        for (int i = t; i < ecnt; i += 256) {
            uint2 e = img[i];
            adj[ebase + i] = make_int2((int)e.x, (int)e.y);
        }
    } else {
        for (int i = t; i < ecnt; i += 256) {
            uint2 e = stage[ebase + i];
            int dl = (e.x >> 23) & 255;
            int p = atomicAdd(&cursor[nb0 + dl], 1);
            adj[p] = make_int2((int)(e.x & 0x7fffffu), (int)e.y);
        }
    }
}

// ---------------- generic fallback path (N > 65536 only) ----------------

__global__ void histn_k(const int* __restrict__ dst, int* __restrict__ cnt, int E) {
    int i = blockIdx.x * blockDim.x + threadIdx.x;
    if (i < E) atomicAdd(&cnt[dst[i]], 1);
}

__global__ void partial_k(const int* __restrict__ cnt, int* __restrict__ bsum, int N) {
    int t = threadIdx.x, b = blockIdx.x;
    int base = b * 1024 + t * 4;
    int s = 0;
    if (base + 4 <= N) {
        int4 v = *(const int4*)(cnt + base);
        s = v.x + v.y + v.z + v.w;
    } else {
        for (int j = 0; j < 4; ++j)
            if (base + j < N) s += cnt[base + j];
    }
    __shared__ int sm[256];
    sm[t] = s;
    __syncthreads();
    for (int off = 128; off > 0; off >>= 1) {
        if (t < off) sm[t] += sm[t + off];
        __syncthreads();
    }
    if (t == 0) bsum[b] = sm[0];
}

__global__ void scanb_k(const int* __restrict__ bsum, int* __restrict__ boff,
                        int* __restrict__ rowptr, int nb, int N) {
    int t = threadIdx.x;
    int v = (t < nb) ? bsum[t] : 0;
    __shared__ int sm[256];
    sm[t] = v;
    __syncthreads();
    for (int off = 1; off < 256; off <<= 1) {
        int u = (t >= off) ? sm[t - off] : 0;
        __syncthreads();
        sm[t] += u;
        __syncthreads();
    }
    if (t < nb) boff[t] = sm[t] - v;
    if (t == 255) rowptr[N] = sm[255];
}

__global__ void rowfill_k(const int* __restrict__ cnt, const int* __restrict__ boff,
                          int* __restrict__ rowptr, int* __restrict__ cursor, int N) {
    int t = threadIdx.x, b = blockIdx.x;
    int base = b * 1024 + t * 4;
    int c0 = 0, c1 = 0, c2 = 0, c3 = 0;
    if (base + 4 <= N) {
        int4 v = *(const int4*)(cnt + base);
        c0 = v.x; c1 = v.y; c2 = v.z; c3 = v.w;
    } else {
        if (base + 0 < N) c0 = cnt[base + 0];
        if (base + 1 < N) c1 = cnt[base + 1];
        if (base + 2 < N) c2 = cnt[base + 2];
        if (base + 3 < N) c3 = cnt[base + 3];
    }
    int s = c0 + c1 + c2 + c3;
    __shared__ int sm[256];
    sm[t] = s;
    __syncthreads();
    for (int off = 1; off < 256; off <<= 1) {
        int u = (t >= off) ? sm[t - off] : 0;
        __syncthreads();
        sm[t] += u;
        __syncthreads();
    }
    int run = boff[b] + sm[t] - s;
    if (base + 0 < N) { rowptr[base + 0] = run; cursor[base + 0] = run; run += c0; }
    if (base + 1 < N) { rowptr[base + 1] = run; cursor[base + 1] = run; run += c1; }
    if (base + 2 < N) { rowptr[base + 2] = run; cursor[base + 2] = run; run += c2; }
    if (base + 3 < N) { rowptr[base + 3] = run; cursor[base + 3] = run; run += c3; }
}

__global__ void fill_k(const int* __restrict__ src, const int* __restrict__ dst,
                       const float* __restrict__ ew, int* __restrict__ cursor,
                       int2* __restrict__ adj, int E) {
    int i = blockIdx.x * blockDim.x + threadIdx.x;
    if (i < E) {
        int p = atomicAdd(&cursor[dst[i]], 1);
        int2 e;
        e.x = src[i];
        e.y = __float_as_int(ew[i]);
        adj[p] = e;
    }
}

// ---- fused aggregation + MFMA: one block per 16-row strip ----
// Phase 1 (4 waves): wave w aggregates nodes w, w+4, w+8, w+12 (uint4 gather,
//   4 edge-slot groups x 16 col-lanes), stages mean'd bf16 row into LDS
//   (pad-136 rows: stride 272B = 17x16B -> <=2-way bank aliasing).
//   Self-term (layer 2) loaded by g==0 ONLY: the group butterfly sums over
//   4 groups, so loading in all groups would count it 4x (R14 bug).
// Phase 2 (wave 0): MFMA A-frags from LDS, B from Wt; epilogue per layer.
// A frag: row=lane&15, k=(lane>>4)*8+j ; D: col=lane&15, row=(lane>>4)*4+reg.

__device__ __forceinline__ float gelu_exact(float v) {
    return 0.5f * v * (1.0f + erff(v * 0.70710678118654752440f));
}

template <int SELF>  // 0: layer1 -> bf16 out ; 1: layer2 (+residual+LN+GELU) -> f32 out
__global__ __launch_bounds__(256) void aggmm_k(
    const uint4* __restrict__ xin4, const int* __restrict__ rowptr,
    const int2* __restrict__ adj, const ushort* __restrict__ Wt,
    const float* __restrict__ bl, const float* __restrict__ gamma,
    const float* __restrict__ beta, ushort* __restrict__ outb,
    float* __restrict__ outf, int N) {
    __shared__ __align__(16) ushort rows[16][136];
    __shared__ float wbs[16];
    int t = threadIdx.x;
    int wv = t >> 6;
    int lane = t & 63;
    int row0 = blockIdx.x << 4;
    int g = lane >> 4, c = lane & 15;

#define FMA8(V, W)                                                        \
    do {                                                                  \
        a0 += (W) * bf2f((V).x & 0xffffu); a1 += (W) * bf2f((V).x >> 16); \
        a2 += (W) * bf2f((V).y & 0xffffu); a3 += (W) * bf2f((V).y >> 16); \
        a4 += (W) * bf2f((V).z & 0xffffu); a5 += (W) * bf2f((V).z >> 16); \
        a6 += (W) * bf2f((V).w & 0xffffu); a7 += (W) * bf2f((V).w >> 16); \
    } while (0)

    for (int q = 0; q < 4; ++q) {
        int i = wv + q * 4;  // node slot 0..15
        int node = row0 + i;
        float a0 = 0.f, a1 = 0.f, a2 = 0.f, a3 = 0.f;
        float a4 = 0.f, a5 = 0.f, a6 = 0.f, a7 = 0.f, ws = 0.f;
        int lo = 0, hi = 0;
        if (node < N) {
            lo = rowptr[node];
            hi = rowptr[node + 1];
            if (SELF && g == 0) {  // self-loop once (butterfly sums 4 groups)
                uint4 v = xin4[(size_t)node * 16 + c];
                a0 = bf2f(v.x & 0xffffu); a1 = bf2f(v.x >> 16);
                a2 = bf2f(v.y & 0xffffu); a3 = bf2f(v.y >> 16);
                a4 = bf2f(v.z & 0xffffu); a5 = bf2f(v.z >> 16);
                a6 = bf2f(v.w & 0xffffu); a7 = bf2f(v.w >> 16);
            }
        }
        for (int base = lo; base < hi; base += 64) {
            int p = base + lane;
            int sidx = 0; float wv2 = 0.f;
            if (p < hi) {
                int2 e = adj[p];
                sidx = e.x;
                wv2 = __int_as_float(e.y);
            }
            ws += wv2;
            int cnt = min(hi - base, 64);
            int j = 0;
            for (; j + 16 <= cnt; j += 16) {
                int s0 = __shfl(sidx, j + g),     s1 = __shfl(sidx, j + 4 + g);
                int s2 = __shfl(sidx, j + 8 + g), s3 = __shfl(sidx, j + 12 + g);
                float w0 = __shfl(wv2, j + g),     w1 = __shfl(wv2, j + 4 + g);
                float w2 = __shfl(wv2, j + 8 + g), w3 = __shfl(wv2, j + 12 + g);
                uint4 v0 = xin4[(size_t)s0 * 16 + c];
                uint4 v1 = xin4[(size_t)s1 * 16 + c];
                uint4 v2 = xin4[(size_t)s2 * 16 + c];
                uint4 v3 = xin4[(size_t)s3 * 16 + c];
                FMA8(v0, w0); FMA8(v1, w1); FMA8(v2, w2); FMA8(v3, w3);
            }
            for (; j < cnt; j += 4) {
                // phantom slots (j+g >= cnt) carry sidx=0, wv2=0 -> harmless
                int s0 = __shfl(sidx, j + g);
                float w0 = __shfl(wv2, j + g);
                uint4 v0 = xin4[(size_t)s0 * 16 + c];
                FMA8(v0, w0);
            }
        }
        // combine 4 edge-slot groups (butterfly leaves sum in all lanes)
        a0 += __shfl_xor(a0, 16); a0 += __shfl_xor(a0, 32);
        a1 += __shfl_xor(a1, 16); a1 += __shfl_xor(a1, 32);
        a2 += __shfl_xor(a2, 16); a2 += __shfl_xor(a2, 32);
        a3 += __shfl_xor(a3, 16); a3 += __shfl_xor(a3, 32);
        a4 += __shfl_xor(a4, 16); a4 += __shfl_xor(a4, 32);
        a5 += __shfl_xor(a5, 16); a5 += __shfl_xor(a5, 32);
        a6 += __shfl_xor(a6, 16); a6 += __shfl_xor(a6, 32);
        a7 += __shfl_xor(a7, 16); a7 += __shfl_xor(a7, 32);
        ws += __shfl_xor(ws, 1);
        ws += __shfl_xor(ws, 2);
        ws += __shfl_xor(ws, 4);
        ws += __shfl_xor(ws, 8);
        ws += __shfl_xor(ws, 16);
        ws += __shfl_xor(ws, 32);
        int deg = hi - lo;
        float inv, wb;
        if (SELF) {
            inv = 1.0f / (float)(deg + 1);
            wb = (ws + 1.0f) * inv;
        } else {
            float dd = fmaxf((float)deg, 1.0f);
            inv = 1.0f / dd;
            wb = ws / dd;
        }
        if (g == 0) {
            uint4 o;
            o.x = f2bf(a0 * inv) | (f2bf(a1 * inv) << 16);
            o.y = f2bf(a2 * inv) | (f2bf(a3 * inv) << 16);
            o.z = f2bf(a4 * inv) | (f2bf(a5 * inv) << 16);
            o.w = f2bf(a6 * inv) | (f2bf(a7 * inv) << 16);
            *reinterpret_cast<uint4*>(&rows[i][c * 8]) = o;
            if (c == 0) wbs[i] = wb;
        }
    }
#undef FMA8
    __syncthreads();
    if (wv != 0) return;

    // wave 0: MFMA over the strip
    int kg = g << 3;
    bf16x8 af[4];
#pragma unroll
    for (int kc = 0; kc < 4; ++kc)
        af[kc] = *(const bf16x8*)&rows[c][kc * 32 + kg];

    f32x4 acc[8];
#pragma unroll
    for (int nt = 0; nt < 8; ++nt) {
        f32x4 a = {0.f, 0.f, 0.f, 0.f};
#pragma unroll
        for (int kc = 0; kc < 4; ++kc) {
            bf16x8 bf = *(const bf16x8*)(Wt + (size_t)(nt * 16 + c) * DF + kc * 32 + kg);
            a = __builtin_amdgcn_mfma_f32_16x16x32_bf16(af[kc], bf, a, 0, 0, 0);
        }
        acc[nt] = a;
    }

    const ushort* xin_s = (const ushort*)xin4;
#pragma unroll
    for (int r = 0; r < 4; ++r) {
        int i = g * 4 + r;
        int R = row0 + i;
        if (R >= N) continue;
        float wb = wbs[i];
        if (!SELF) {
#pragma unroll
            for (int nt = 0; nt < 8; ++nt) {
                int col = nt * 16 + c;
                outb[(size_t)R * DF + col] = (ushort)f2bf(acc[nt][r] + bl[col] * wb);
            }
        } else {
            float pre[8];
            float s = 0.f;
#pragma unroll
            for (int nt = 0; nt < 8; ++nt) {
                int col = nt * 16 + c;
                pre[nt] = acc[nt][r] + bl[col] * wb + bf2f(xin_s[(size_t)R * DF + col]);
                s += pre[nt];
            }
            s += __shfl_xor(s, 1);
            s += __shfl_xor(s, 2);
            s += __shfl_xor(s, 4);
            s += __shfl_xor(s, 8);
            float mu = s * (1.0f / 128.0f);
            float vs = 0.f;
#pragma unroll
            for (int nt = 0; nt < 8; ++nt) {
                float d = pre[nt] - mu;
                vs += d * d;
            }
            vs += __shfl_xor(vs, 1);
            vs += __shfl_xor(vs, 2);
            vs += __shfl_xor(vs, 4);
            vs += __shfl_xor(vs, 8);
            float rstd = rsqrtf(vs * (1.0f / 128.0f) + 1e-5f);
#pragma unroll
            for (int nt = 0; nt < 8; ++nt) {
                int col = nt * 16 + c;
                float y = (pre[nt] - mu) * rstd * gamma[col] + beta[col];
                outf[(size_t)R * DF + col] = gelu_exact(y);
            }
        }
    }
}

// ---------------- launch ----------------

extern "C" void kernel_launch(void* const* d_in, const int* in_sizes, int n_in,
                              void* d_out, int out_size, void* d_ws, size_t ws_size,
                              hipStream_t stream) {
    const float* x     = (const float*)d_in[0];
    const int*   ei    = (const int*)d_in[1];
    const float* ew    = (const float*)d_in[2];
    const float* Wl1   = (const float*)d_in[3];
    const float* bl1   = (const float*)d_in[4];
    const float* Wl2   = (const float*)d_in[5];
    const float* bl2   = (const float*)d_in[6];
    const float* gamma = (const float*)d_in[7];
    const float* beta  = (const float*)d_in[8];
    float* out = (float*)d_out;

    int N = in_sizes[0] / DF;
    int E = in_sizes[2];
    const int* src = ei;
    const int* dst = ei + E;

    char* ws = (char*)d_ws;
    size_t off = 0;
    auto alloc = [&](size_t bytes) -> void* {
        void* p = ws + off;
        off += (bytes + 255) & ~(size_t)255;
        return p;
    };
    int histB = (E + EPB - 1) / EPB;
    int*    rowptr  = (int*)alloc((size_t)(N + 1) * 4);
    int*    cursor  = (int*)alloc((size_t)N * 4);
    int*    bhist   = (int*)alloc((size_t)histB * 256 * 4);
    int*    bkoff   = (int*)alloc(1040);
    int*    gcur    = (int*)alloc(1024);
    int*    bsum    = (int*)alloc(1024);
    int*    boff    = (int*)alloc(1024);
    int2*   adj     = (int2*)alloc((size_t)E * 8);
    uint2*  stage   = (uint2*)alloc((size_t)E * 8);
    uint*   xb      = (uint*)alloc((size_t)N * DF * 2);
    ushort* x1b     = (ushort*)alloc((size_t)N * DF * 2);
    uint*   Wt1     = (uint*)alloc((size_t)DF * DF * 2);
    uint*   Wt2     = (uint*)alloc((size_t)DF * DF * 2);
    int*    cnt     = (int*)alloc((size_t)N * 4);  // fallback path only

    int nbk = (N + NPB - 1) / NPB;
    int n4 = N * DF / 4;
    int cvtxB = (n4 + 255) / 256;

    if (nbk <= 256) {
        hipLaunchKernelGGL(prep_k, dim3(cvtxB + 64 + histB), dim3(256), 0, stream,
                           x, xb, n4, Wl1, Wl2, Wt1, Wt2, dst, bhist, E, cvtxB);
        hipLaunchKernelGGL(bscan_k, dim3(1), dim3(256), 0, stream, bhist, histB, bkoff, gcur);
        int aB = (E + EPBA - 1) / EPBA;
        hipLaunchKernelGGL(passA_k, dim3(aB), dim3(256), 0, stream, src, dst, ew, gcur, stage, E);
        hipLaunchKernelGGL(passB_k, dim3(nbk), dim3(256), 0, stream,
                           stage, bkoff, rowptr, cursor, adj, N, nbk);
    } else {  // generic fallback (not taken for this problem size)
        hipMemsetAsync(cnt, 0, (size_t)N * 4, stream);
        hipLaunchKernelGGL(prep_k, dim3(cvtxB + 64), dim3(256), 0, stream,
                           x, xb, n4, Wl1, Wl2, Wt1, Wt2, dst, bhist, 0, cvtxB);
        int eb = (E + 255) / 256;
        hipLaunchKernelGGL(histn_k, dim3(eb), dim3(256), 0, stream, dst, cnt, E);
        int nb_scan = (N + 1023) / 1024;
        hipLaunchKernelGGL(partial_k, dim3(nb_scan), dim3(256), 0, stream, cnt, bsum, N);
        hipLaunchKernelGGL(scanb_k, dim3(1), dim3(256), 0, stream, bsum, boff, rowptr, nb_scan, N);
        hipLaunchKernelGGL(rowfill_k, dim3(nb_scan), dim3(256), 0, stream, cnt, boff, rowptr, cursor, N);
        hipLaunchKernelGGL(fill_k, dim3(eb), dim3(256), 0, stream, src, dst, ew, cursor, adj, E);
    }

    int nstrips = (N + 15) / 16;
    hipLaunchKernelGGL(aggmm_k<0>, dim3(nstrips), dim3(256), 0, stream,
                       (const uint4*)xb, rowptr, adj, (const ushort*)Wt1, bl1,
                       gamma, beta, x1b, (float*)nullptr, N);
    hipLaunchKernelGGL(aggmm_k<1>, dim3(nstrips), dim3(256), 0, stream,
                       (const uint4*)x1b, rowptr, adj, (const ushort*)Wt2, bl2,
                       gamma, beta, (ushort*)nullptr, out, N);
}